// Round 11
// baseline (714.237 us; speedup 1.0000x reference)
//
#include <hip/hip_runtime.h>
#include <math.h>

#define NV 50000
#define ETR 800000
#define EPOS 200000
#define ETEST 400000
#define NTH 262144   // prep: 256 blocks x 1024 threads

typedef __attribute__((ext_vector_type(8))) short bf16x8;
typedef __attribute__((ext_vector_type(8))) unsigned short ushortx8;
typedef __attribute__((ext_vector_type(4))) float f32x4;

__device__ inline unsigned short f2b(float f) {
    union { float f; unsigned u; } v; v.f = f;
    unsigned r = v.u + 0x7fffu + ((v.u >> 16) & 1u);   // RNE
    return (unsigned short)(r >> 16);
}
__device__ inline float blo(unsigned q) { union { unsigned u; float f; } v; v.u = q << 16; return v.f; }
__device__ inline float bhi(unsigned q) { union { unsigned u; float f; } v; v.u = q & 0xffff0000u; return v.f; }
__device__ inline float b2f(unsigned short s) { union { unsigned u; float f; } v; v.u = ((unsigned)s) << 16; return v.f; }

__device__ inline ushortx8 bf16add8(ushortx8 a, ushortx8 b) {
    ushortx8 r;
    #pragma unroll
    for (int i = 0; i < 8; ++i)
        r[i] = f2b(b2f(a[i]) + b2f(b[i]));
    return r;
}

// global spin barrier: all gridDim.x blocks guaranteed co-resident (256 blocks on 256 CUs)
__device__ inline void gbar(int* cnt, int target) {
    __threadfence();
    __syncthreads();
    if (threadIdx.x == 0) {
        atomicAdd(cnt, 1);
        while (atomicAdd(cnt, 0) < target) __builtin_amdgcn_s_sleep(8);
    }
    __syncthreads();
    __threadfence();
}

// ---------------- fused prep: cvt weights + CSR(train) + sort(test) ----------------
// P1: weight converts + deg/tdeg histograms | bar
// P2: partial sums | bar | scans -> ptr/cursor/dinv + tptr/tcursor | bar
// P3: fill edat (train) + eab/eorig (test, sorted by a-endpoint)

__global__ __launch_bounds__(1024) void prep_kernel(
    const int* __restrict__ tei, const int* __restrict__ pos, const int* __restrict__ neg,
    const float* __restrict__ W1, const float* __restrict__ W2, const float* __restrict__ Wl1,
    unsigned short* __restrict__ w1t, unsigned short* __restrict__ w2t, unsigned short* __restrict__ wl1t,
    int* __restrict__ deg, int* __restrict__ tdeg,
    int* __restrict__ ptr, int* __restrict__ cursor,
    int* __restrict__ tptr, int* __restrict__ tcursor,
    float* __restrict__ dinv, int* __restrict__ partials, int* __restrict__ tpartials,
    int2* __restrict__ edat, int2* __restrict__ eab, int* __restrict__ eorig,
    int* __restrict__ bars)
{
    int b = blockIdx.x, t = threadIdx.x;
    int gtid = b * 1024 + t;

    // ---- P1: weight converts (one elem per low thread) + histograms (grid-stride)
    if (gtid < 65536) {
        w1t[gtid] = f2b(W1[(gtid & 255) * 256 + (gtid >> 8)]);
    } else if (gtid < 98304) {
        int i = gtid - 65536;
        w2t[i] = f2b(W2[(i & 255) * 128 + (i >> 8)]);
    } else if (gtid < 106496) {
        int i = gtid - 98304;
        wl1t[i] = f2b(Wl1[(i & 127) * 64 + (i >> 7)]);
    }
    for (int e = gtid; e < ETR; e += NTH)
        atomicAdd(&deg[tei[ETR + e]], 1);
    for (int e = gtid; e < ETEST; e += NTH) {
        int a = (e < EPOS) ? pos[e] : neg[e - EPOS];
        atomicAdd(&tdeg[a], 1);
    }
    gbar(bars + 0, gridDim.x);

    // ---- P2a: per-block chunk sums (chunk = 196 nodes)
    int i = b * 196 + t;
    int d = 0, td = 0;
    if (t < 196 && i < NV) { d = deg[i]; td = tdeg[i]; }
    __shared__ int s1[256], s2[256];
    __shared__ int base1, base2;
    if (t < 256) { s1[t] = d; s2[t] = td; }
    __syncthreads();
    for (int off = 128; off > 0; off >>= 1) {
        if (t < off) { s1[t] += s1[t + off]; s2[t] += s2[t + off]; }
        __syncthreads();
    }
    if (t == 0) { partials[b] = s1[0]; tpartials[b] = s2[0]; }
    gbar(bars + 1, gridDim.x);

    // ---- P2b: block base + intra-chunk inclusive scan (Hillis-Steele over 256)
    if (t == 0) {
        int s = 0, ts = 0;
        for (int k = 0; k < b; ++k) { s += partials[k]; ts += tpartials[k]; }
        base1 = s; base2 = ts;
    }
    if (t < 256) { s1[t] = d; s2[t] = td; }
    __syncthreads();
    for (int off = 1; off < 256; off <<= 1) {
        int v1 = 0, v2 = 0;
        if (t < 256 && t >= off) { v1 = s1[t - off]; v2 = s2[t - off]; }
        __syncthreads();
        if (t < 256) { s1[t] += v1; s2[t] += v2; }
        __syncthreads();
    }
    if (t < 196 && i < NV) {
        int e1 = base1 + s1[t] - d;
        int e2 = base2 + s2[t] - td;
        ptr[i] = e1;  cursor[i] = e1;
        tptr[i] = e2; tcursor[i] = e2;
        dinv[i] = rsqrtf((float)d + 2.0f);   // SELF_LOOP_W = 2
        if (i == NV - 1) ptr[NV] = e1 + d;
    }
    gbar(bars + 2, gridDim.x);

    // ---- P3: fills (full machine, grid-stride)
    for (int e = gtid; e < ETR; e += NTH) {
        int row = tei[e], col = tei[ETR + e];
        int p = atomicAdd(&cursor[col], 1);
        edat[p] = make_int2(row, __float_as_int(dinv[row] * dinv[col]));
    }
    for (int e = gtid; e < ETEST; e += NTH) {
        int a, bb;
        if (e < EPOS) { a = pos[e]; bb = pos[EPOS + e]; }
        else { int i2 = e - EPOS; a = neg[i2]; bb = neg[EPOS + i2]; }
        int p = atomicAdd(&tcursor[a], 1);
        eab[p] = make_int2(a, bb);
        eorig[p] = e;
    }
}

// ---------------- shared GEMM body (128x128 tile, 4 waves 2x2, BK=64, swizzled LDS) ----------------

template<int N, int K, bool AF32>
__device__ __forceinline__ void gemm_body(
    const void* __restrict__ Av, const unsigned short* __restrict__ Bt,
    unsigned short* __restrict__ C, int M, int row0, int col0)
{
    constexpr int BK = 64;
    __shared__ unsigned short Asm[128][BK];
    __shared__ unsigned short Bsm[128][BK];
    int tid = threadIdx.x;
    int lane = tid & 63, wid = tid >> 6;
    int wr = wid >> 1, wc = wid & 1;

    int sr = tid >> 3;
    int s8 = tid & 7;
    int sswz = s8 ^ (sr & 7);
    int fr = lane & 15;
    int g  = lane >> 4;

    f32x4 acc[4][4] = {};

    for (int k0 = 0; k0 < K; k0 += BK) {
        #pragma unroll
        for (int i = 0; i < 4; ++i) {
            int r = sr + i * 32;
            int gr = row0 + r;
            ushortx8 va = {0, 0, 0, 0, 0, 0, 0, 0};
            if constexpr (AF32) {
                const float* Af = (const float*)Av;
                if (gr < M) {
                    float4 f0 = *(const float4*)&Af[(size_t)gr * K + k0 + s8 * 8];
                    float4 f1 = *(const float4*)&Af[(size_t)gr * K + k0 + s8 * 8 + 4];
                    va[0] = f2b(f0.x); va[1] = f2b(f0.y); va[2] = f2b(f0.z); va[3] = f2b(f0.w);
                    va[4] = f2b(f1.x); va[5] = f2b(f1.y); va[6] = f2b(f1.z); va[7] = f2b(f1.w);
                }
            } else {
                const unsigned short* Ab = (const unsigned short*)Av;
                if (gr < M) va = *(const ushortx8*)&Ab[(size_t)gr * K + k0 + s8 * 8];
            }
            *(ushortx8*)&Asm[r][sswz * 8] = va;
            ushortx8 vb = *(const ushortx8*)&Bt[(size_t)(col0 + r) * K + k0 + s8 * 8];
            *(ushortx8*)&Bsm[r][sswz * 8] = vb;
        }
        __syncthreads();
        #pragma unroll
        for (int kf = 0; kf < BK; kf += 32) {
            int sbase = kf >> 3;
            bf16x8 af[4], bfr[4];
            #pragma unroll
            for (int m = 0; m < 4; ++m) {
                int rr = wr * 64 + m * 16 + fr;
                af[m] = *(const bf16x8*)&Asm[rr][((sbase + g) ^ (fr & 7)) * 8];
            }
            #pragma unroll
            for (int n = 0; n < 4; ++n) {
                int rr = wc * 64 + n * 16 + fr;
                bfr[n] = *(const bf16x8*)&Bsm[rr][((sbase + g) ^ (fr & 7)) * 8];
            }
            #pragma unroll
            for (int m = 0; m < 4; ++m)
                #pragma unroll
                for (int n = 0; n < 4; ++n)
                    acc[m][n] = __builtin_amdgcn_mfma_f32_16x16x32_bf16(af[m], bfr[n], acc[m][n], 0, 0, 0);
        }
        __syncthreads();
    }

    // C/D layout: col = lane&15, row = (lane>>4)*4 + j
    #pragma unroll
    for (int m = 0; m < 4; ++m) {
        int rbase = row0 + wr * 64 + m * 16 + g * 4;
        #pragma unroll
        for (int j = 0; j < 4; ++j) {
            int r = rbase + j;
            if (r < M) {
                #pragma unroll
                for (int n = 0; n < 4; ++n) {
                    int c = col0 + wc * 64 + n * 16 + fr;
                    C[(size_t)r * N + c] = f2b(acc[m][n][j]);
                }
            }
        }
    }
}

__global__ __launch_bounds__(256) void gemm1_kernel(
    const float* __restrict__ x, const unsigned short* __restrict__ w1t,
    unsigned short* __restrict__ C)
{
    // adjacent blocks share the A row-panel (L2 reuse)
    int row0 = (blockIdx.x >> 1) * 128, col0 = (blockIdx.x & 1) * 128;
    gemm_body<256, 256, true>(x, w1t, C, NV, row0, col0);
}

__global__ __launch_bounds__(256) void gemm2_kernel(
    const unsigned short* __restrict__ A, const unsigned short* __restrict__ Bt,
    unsigned short* __restrict__ C)
{
    gemm_body<128, 256, false>(A, Bt, C, NV, blockIdx.x * 128, 0);
}

// ---------------- gather (bf16 in/out), 8-way edge unroll + NT stores ----------------

template<int F, bool RELU>
__global__ __launch_bounds__(256) void gather_kernel(
    const int* __restrict__ ptr, const int2* __restrict__ edat,
    const float* __restrict__ dinv, const unsigned short* __restrict__ hlin,
    const float* __restrict__ bias, unsigned short* __restrict__ hout)
{
    constexpr int V = F / 64;
    int gid = blockIdx.x * blockDim.x + threadIdx.x;
    int node = gid >> 6, lane = gid & 63;
    if (node >= NV) return;
    float dc = dinv[node];
    int j0 = ptr[node], j1 = ptr[node + 1];
    float acc[V] = {};
    const unsigned short* hb = hlin + lane * V;
    const long long* edl = (const long long*)edat;

    int j = j0;
    for (; j + 7 < j1; j += 8) {
        long long e[8];
        #pragma unroll
        for (int u = 0; u < 8; ++u) e[u] = __builtin_nontemporal_load(edl + j + u);
        if constexpr (V == 4) {
            uint2 q[8];
            #pragma unroll
            for (int u = 0; u < 8; ++u)
                q[u] = *(const uint2*)(hb + (size_t)(int)e[u] * F);
            #pragma unroll
            for (int u = 0; u < 8; ++u) {
                float n = __int_as_float((int)(e[u] >> 32));
                acc[0] += n * blo(q[u].x);
                acc[1] += n * bhi(q[u].x);
                acc[2] += n * blo(q[u].y);
                acc[3] += n * bhi(q[u].y);
            }
        } else {
            unsigned q[8];
            #pragma unroll
            for (int u = 0; u < 8; ++u)
                q[u] = *(const unsigned*)(hb + (size_t)(int)e[u] * F);
            #pragma unroll
            for (int u = 0; u < 8; ++u) {
                float n = __int_as_float((int)(e[u] >> 32));
                acc[0] += n * blo(q[u]);
                acc[1] += n * bhi(q[u]);
            }
        }
    }
    for (; j + 3 < j1; j += 4) {
        long long e[4];
        #pragma unroll
        for (int u = 0; u < 4; ++u) e[u] = __builtin_nontemporal_load(edl + j + u);
        if constexpr (V == 4) {
            uint2 q[4];
            #pragma unroll
            for (int u = 0; u < 4; ++u)
                q[u] = *(const uint2*)(hb + (size_t)(int)e[u] * F);
            #pragma unroll
            for (int u = 0; u < 4; ++u) {
                float n = __int_as_float((int)(e[u] >> 32));
                acc[0] += n * blo(q[u].x);
                acc[1] += n * bhi(q[u].x);
                acc[2] += n * blo(q[u].y);
                acc[3] += n * bhi(q[u].y);
            }
        } else {
            unsigned q[4];
            #pragma unroll
            for (int u = 0; u < 4; ++u)
                q[u] = *(const unsigned*)(hb + (size_t)(int)e[u] * F);
            #pragma unroll
            for (int u = 0; u < 4; ++u) {
                float n = __int_as_float((int)(e[u] >> 32));
                acc[0] += n * blo(q[u]);
                acc[1] += n * bhi(q[u]);
            }
        }
    }
    for (; j < j1; ++j) {
        long long e0 = __builtin_nontemporal_load(edl + j);
        float n0 = __int_as_float((int)(e0 >> 32));
        if constexpr (V == 4) {
            uint2 q0 = *(const uint2*)(hb + (size_t)(int)e0 * F);
            acc[0] += n0 * blo(q0.x);
            acc[1] += n0 * bhi(q0.x);
            acc[2] += n0 * blo(q0.y);
            acc[3] += n0 * bhi(q0.y);
        } else {
            unsigned q0 = *(const unsigned*)(hb + (size_t)(int)e0 * F);
            acc[0] += n0 * blo(q0);
            acc[1] += n0 * bhi(q0);
        }
    }

    const unsigned short* ps = hb + (size_t)node * F;
    float sw = 2.0f * dc * dc;
    if constexpr (V == 4) {
        uint2 qs = *(const uint2*)ps;
        float o0 = acc[0] + sw * blo(qs.x) + bias[lane * 4 + 0];
        float o1 = acc[1] + sw * bhi(qs.x) + bias[lane * 4 + 1];
        float o2 = acc[2] + sw * blo(qs.y) + bias[lane * 4 + 2];
        float o3 = acc[3] + sw * bhi(qs.y) + bias[lane * 4 + 3];
        if (RELU) {
            o0 = fmaxf(o0, 0.f); o1 = fmaxf(o1, 0.f);
            o2 = fmaxf(o2, 0.f); o3 = fmaxf(o3, 0.f);
        }
        union { unsigned short u[4]; unsigned long long ll; } pk;
        pk.u[0] = f2b(o0); pk.u[1] = f2b(o1); pk.u[2] = f2b(o2); pk.u[3] = f2b(o3);
        __builtin_nontemporal_store(pk.ll, (unsigned long long*)(hout + (size_t)node * F + lane * 4));
    } else {
        unsigned qs = *(const unsigned*)ps;
        float o0 = acc[0] + sw * blo(qs) + bias[lane * 2 + 0];
        float o1 = acc[1] + sw * bhi(qs) + bias[lane * 2 + 1];
        if (RELU) { o0 = fmaxf(o0, 0.f); o1 = fmaxf(o1, 0.f); }
        union { unsigned short u[2]; unsigned q; } pk;
        pk.u[0] = f2b(o0); pk.u[1] = f2b(o1);
        __builtin_nontemporal_store(pk.q, (unsigned*)(hout + (size_t)node * F + lane * 2));
    }
}

// ---------------- edge MLP via MFMA (sorted edges, scattered out) ----------------

__global__ __launch_bounds__(256) void edge_mlp_mfma_kernel(
    const int2* __restrict__ eab, const int* __restrict__ eorig,
    const unsigned short* __restrict__ h2, const unsigned short* __restrict__ Wl1t,
    const float* __restrict__ bl1, const float* __restrict__ Wl2,
    const float* __restrict__ bl2, float* __restrict__ out)
{
    __shared__ unsigned short Es[128][128];
    __shared__ unsigned short Ws[64][128];
    int tid = threadIdx.x;
    int lane = tid & 63, w = tid >> 6;
    int fr = lane & 15, g = lane >> 4;
    int e0 = blockIdx.x * 128;

    #pragma unroll
    for (int k = 0; k < 4; ++k) {
        int chunk = tid + k * 256;
        int row = chunk >> 4, c = chunk & 15;
        *(ushortx8*)&Ws[row][(c ^ (row & 7)) * 8] = *(const ushortx8*)&Wl1t[chunk * 8];
    }

    int et = tid >> 1, hh = tid & 1;
    int2 ab = eab[e0 + et];          // sorted by a: consecutive edges share a-rows (L2 hits)
    const unsigned short* pa = h2 + (size_t)ab.x * 128 + hh * 64;
    const unsigned short* pb = h2 + (size_t)ab.y * 128 + hh * 64;
    #pragma unroll
    for (int c8 = 0; c8 < 8; ++c8) {
        ushortx8 va = *(const ushortx8*)&pa[c8 * 8];
        ushortx8 vb = *(const ushortx8*)&pb[c8 * 8];
        ushortx8 vs = bf16add8(va, vb);
        int c = hh * 8 + c8;
        *(ushortx8*)&Es[et][(c ^ (et & 7)) * 8] = vs;
    }
    __syncthreads();

    f32x4 acc[2][4] = {};
    #pragma unroll
    for (int ks = 0; ks < 4; ++ks) {
        int c = ks * 4 + g;
        bf16x8 af[2], bfr[4];
        #pragma unroll
        for (int m = 0; m < 2; ++m) {
            int r = w * 32 + m * 16 + fr;
            af[m] = *(const bf16x8*)&Es[r][(c ^ (r & 7)) * 8];
        }
        #pragma unroll
        for (int n = 0; n < 4; ++n) {
            int r = n * 16 + fr;
            bfr[n] = *(const bf16x8*)&Ws[r][(c ^ (r & 7)) * 8];
        }
        #pragma unroll
        for (int m = 0; m < 2; ++m)
            #pragma unroll
            for (int n = 0; n < 4; ++n)
                acc[m][n] = __builtin_amdgcn_mfma_f32_16x16x32_bf16(af[m], bfr[n], acc[m][n], 0, 0, 0);
    }

    float bl2v = bl2[0];
    float b1v[4], w2v[4];
    #pragma unroll
    for (int n = 0; n < 4; ++n) {
        b1v[n] = bl1[n * 16 + fr];
        w2v[n] = Wl2[n * 16 + fr];
    }
    #pragma unroll
    for (int m = 0; m < 2; ++m) {
        float p[4];
        #pragma unroll
        for (int j = 0; j < 4; ++j) {
            float s = 0.f;
            #pragma unroll
            for (int n = 0; n < 4; ++n)
                s += fmaxf(acc[m][n][j] + b1v[n], 0.0f) * w2v[n];
            p[j] = s;
        }
        #pragma unroll
        for (int off = 1; off < 16; off <<= 1) {
            #pragma unroll
            for (int j = 0; j < 4; ++j)
                p[j] += __shfl_xor(p[j], off);
        }
        int ebase = e0 + w * 32 + m * 16 + g * 4;
        #pragma unroll
        for (int j = 0; j < 4; ++j)
            if (fr == j)
                out[eorig[ebase + j]] = 1.0f / (1.0f + expf(-(p[j] + bl2v)));
    }
}

// ---------------- launch ----------------

extern "C" void kernel_launch(void* const* d_in, const int* in_sizes, int n_in,
                              void* d_out, int out_size, void* d_ws, size_t ws_size,
                              hipStream_t stream) {
    const float* x   = (const float*)d_in[0];
    const int*   tei = (const int*)d_in[1];
    const int*   pos = (const int*)d_in[2];
    const int*   neg = (const int*)d_in[3];
    const float* W1  = (const float*)d_in[4];
    const float* b1  = (const float*)d_in[5];
    const float* W2  = (const float*)d_in[6];
    const float* b2  = (const float*)d_in[7];
    const float* Wl1 = (const float*)d_in[8];
    const float* bl1 = (const float*)d_in[9];
    const float* Wl2 = (const float*)d_in[10];
    const float* bl2 = (const float*)d_in[11];
    float* out = (float*)d_out;

    // workspace layout (4B-word offsets, ~80MB total)
    float* fws = (float*)d_ws;
    int*   iws = (int*)d_ws;
    unsigned short* usws = (unsigned short*)d_ws;
    float* dinv      = fws;                       // [50000]
    // contiguous zero region: deg, tdeg, bars
    int*   deg       = iws + 50000;               // [50000]
    int*   tdeg      = iws + 100000;              // [50000]
    int*   bars      = iws + 150000;              // [64]
    int*   ptr       = iws + 150064;              // [50001]
    int*   cursor    = iws + 200128;              // [50000]
    int*   tptr      = iws + 250128;              // [50001]
    int*   tcursor   = iws + 300160;              // [50000]
    int*   partials  = iws + 350208;              // [256]
    int*   tpartials = iws + 350464;              // [256]
    int2*  edat      = (int2*)(iws + 350720);     // [800000] -> ends 1950720
    int2*  eab       = (int2*)(iws + 1950720);    // [400000] -> ends 2750720
    int*   eorig     = iws + 2750720;             // [400000] -> ends 3150720
    unsigned short* w1t  = usws + 2ull * 3150720; // [65536]  -> w 3183488
    unsigned short* w2t  = usws + 2ull * 3183488; // [32768]  -> w 3199872
    unsigned short* wl1t = usws + 2ull * 3199872; // [8192]   -> w 3203968
    unsigned short* bufX   = usws + 2ull * 3203968;  // h2lin bf16 [6.4M] -> w 6403968
    unsigned short* bufL16 = usws + 2ull * 6403968;  // h1lin, then h2 [12.8M] -> w 12803968
    unsigned short* bufH   = usws + 2ull * 12803968; // h1 [12.8M] -> w 19203968

    // zero deg+tdeg+bars in one shot
    hipMemsetAsync(deg, 0, (100000 + 64) * sizeof(int), stream);

    prep_kernel<<<256, 1024, 0, stream>>>(
        tei, pos, neg, W1, W2, Wl1, w1t, w2t, wl1t,
        deg, tdeg, ptr, cursor, tptr, tcursor,
        dinv, partials, tpartials, edat, eab, eorig, bars);

    // layer 1: h1lin = bf16(x) @ w1t ; gather -> h1
    gemm1_kernel<<<782, 256, 0, stream>>>(x, w1t, bufL16);
    gather_kernel<256, true><<<(NV * 64) / 256, 256, 0, stream>>>(ptr, edat, dinv, bufL16, b1, bufH);

    // layer 2: h2lin = h1 @ w2t ; gather -> h2
    gemm2_kernel<<<391, 256, 0, stream>>>(bufH, w2t, bufX);
    gather_kernel<128, false><<<(NV * 64) / 256, 256, 0, stream>>>(ptr, edat, dinv, bufX, b2, bufL16);

    // edge MLP head (MFMA, a-sorted edges)
    edge_mlp_mfma_kernel<<<ETEST / 128, 256, 0, stream>>>(eab, eorig, bufL16, wl1t, bl1, Wl2, bl2, out);
}

// Round 12
// 326.934 us; speedup vs baseline: 2.1847x; 2.1847x over previous
//
#include <hip/hip_runtime.h>
#include <math.h>

#define NV 50000
#define ETR 800000
#define EPOS 200000
#define ETEST 400000

typedef __attribute__((ext_vector_type(8))) short bf16x8;
typedef __attribute__((ext_vector_type(8))) unsigned short ushortx8;
typedef __attribute__((ext_vector_type(4))) float f32x4;

__device__ inline unsigned short f2b(float f) {
    union { float f; unsigned u; } v; v.f = f;
    unsigned r = v.u + 0x7fffu + ((v.u >> 16) & 1u);   // RNE
    return (unsigned short)(r >> 16);
}
__device__ inline float blo(unsigned q) { union { unsigned u; float f; } v; v.u = q << 16; return v.f; }
__device__ inline float bhi(unsigned q) { union { unsigned u; float f; } v; v.u = q & 0xffff0000u; return v.f; }
__device__ inline float b2f(unsigned short s) { union { unsigned u; float f; } v; v.u = ((unsigned)s) << 16; return v.f; }

__device__ inline ushortx8 bf16add8(ushortx8 a, ushortx8 b) {
    ushortx8 r;
    #pragma unroll
    for (int i = 0; i < 8; ++i)
        r[i] = f2b(b2f(a[i]) + b2f(b[i]));
    return r;
}

// ---------------- shared GEMM body (128x128 tile, 4 waves 2x2, BK=64, swizzled LDS) ----------------

template<int N, int K, bool AF32>
__device__ __forceinline__ void gemm_body(
    const void* __restrict__ Av, const unsigned short* __restrict__ Bt,
    unsigned short* __restrict__ C, int M, int row0, int col0)
{
    constexpr int BK = 64;
    __shared__ unsigned short Asm[128][BK];
    __shared__ unsigned short Bsm[128][BK];
    int tid = threadIdx.x;
    int lane = tid & 63, wid = tid >> 6;
    int wr = wid >> 1, wc = wid & 1;

    int sr = tid >> 3;
    int s8 = tid & 7;
    int sswz = s8 ^ (sr & 7);
    int fr = lane & 15;
    int g  = lane >> 4;

    f32x4 acc[4][4] = {};

    for (int k0 = 0; k0 < K; k0 += BK) {
        #pragma unroll
        for (int i = 0; i < 4; ++i) {
            int r = sr + i * 32;
            int gr = row0 + r;
            ushortx8 va = {0, 0, 0, 0, 0, 0, 0, 0};
            if constexpr (AF32) {
                const float* Af = (const float*)Av;
                if (gr < M) {
                    float4 f0 = *(const float4*)&Af[(size_t)gr * K + k0 + s8 * 8];
                    float4 f1 = *(const float4*)&Af[(size_t)gr * K + k0 + s8 * 8 + 4];
                    va[0] = f2b(f0.x); va[1] = f2b(f0.y); va[2] = f2b(f0.z); va[3] = f2b(f0.w);
                    va[4] = f2b(f1.x); va[5] = f2b(f1.y); va[6] = f2b(f1.z); va[7] = f2b(f1.w);
                }
            } else {
                const unsigned short* Ab = (const unsigned short*)Av;
                if (gr < M) va = *(const ushortx8*)&Ab[(size_t)gr * K + k0 + s8 * 8];
            }
            *(ushortx8*)&Asm[r][sswz * 8] = va;
            ushortx8 vb = *(const ushortx8*)&Bt[(size_t)(col0 + r) * K + k0 + s8 * 8];
            *(ushortx8*)&Bsm[r][sswz * 8] = vb;
        }
        __syncthreads();
        #pragma unroll
        for (int kf = 0; kf < BK; kf += 32) {
            int sbase = kf >> 3;
            bf16x8 af[4], bfr[4];
            #pragma unroll
            for (int m = 0; m < 4; ++m) {
                int rr = wr * 64 + m * 16 + fr;
                af[m] = *(const bf16x8*)&Asm[rr][((sbase + g) ^ (fr & 7)) * 8];
            }
            #pragma unroll
            for (int n = 0; n < 4; ++n) {
                int rr = wc * 64 + n * 16 + fr;
                bfr[n] = *(const bf16x8*)&Bsm[rr][((sbase + g) ^ (fr & 7)) * 8];
            }
            #pragma unroll
            for (int m = 0; m < 4; ++m)
                #pragma unroll
                for (int n = 0; n < 4; ++n)
                    acc[m][n] = __builtin_amdgcn_mfma_f32_16x16x32_bf16(af[m], bfr[n], acc[m][n], 0, 0, 0);
        }
        __syncthreads();
    }

    // C/D layout: col = lane&15, row = (lane>>4)*4 + j
    #pragma unroll
    for (int m = 0; m < 4; ++m) {
        int rbase = row0 + wr * 64 + m * 16 + g * 4;
        #pragma unroll
        for (int j = 0; j < 4; ++j) {
            int r = rbase + j;
            if (r < M) {
                #pragma unroll
                for (int n = 0; n < 4; ++n) {
                    int c = col0 + wc * 64 + n * 16 + fr;
                    C[(size_t)r * N + c] = f2b(acc[m][n][j]);
                }
            }
        }
    }
}

// ---------------- fat0: deg hist (0..3124) + tdeg hist (3125..4687) + cvt W1 (4688..4943) ----------------

__global__ __launch_bounds__(256) void fat0_kernel(
    const int* __restrict__ tei, const int* __restrict__ pos, const int* __restrict__ neg,
    int* __restrict__ deg, int* __restrict__ tdeg,
    const float* __restrict__ W1, unsigned short* __restrict__ w1t)
{
    int bid = blockIdx.x;
    int t = threadIdx.x;
    if (bid < 3125) {
        int e = bid * 256 + t;
        if (e < ETR) atomicAdd(&deg[tei[ETR + e]], 1);
    } else if (bid < 4688) {
        int e = (bid - 3125) * 256 + t;
        if (e < ETEST) {
            int a = (e < EPOS) ? pos[e] : neg[e - EPOS];
            atomicAdd(&tdeg[a], 1);
        }
    } else {
        int i = (bid - 4688) * 256 + t;        // 0..65535
        w1t[i] = f2b(W1[(i & 255) * 256 + (i >> 8)]);
    }
}

// ---------------- fat1: gemm1 (0..781) + partials deg (782..830) + partials tdeg (831..879)
//                       + cvt W2 (880..1007) + cvt Wl1 (1008..1039) ----------------

__global__ __launch_bounds__(256) void fat1_kernel(
    const float* __restrict__ x, const unsigned short* __restrict__ w1t,
    unsigned short* __restrict__ h1lin,
    const int* __restrict__ deg, int* __restrict__ partials,
    const int* __restrict__ tdeg, int* __restrict__ tpartials,
    const float* __restrict__ W2, unsigned short* __restrict__ w2t,
    const float* __restrict__ Wl1, unsigned short* __restrict__ wl1t)
{
    int bid = blockIdx.x;
    int t = threadIdx.x;
    if (bid < 782) {
        int row0 = (bid >> 1) * 128, col0 = (bid & 1) * 128;
        gemm_body<256, 256, true>(x, w1t, h1lin, NV, row0, col0);
    } else if (bid < 880) {
        int p = (bid - 782) % 49;
        const int* src = (bid < 831) ? deg : tdeg;
        int* dst = (bid < 831) ? partials : tpartials;
        int base = p * 1024;
        int s = 0;
        #pragma unroll
        for (int k = 0; k < 4; ++k) {
            int i = base + t + k * 256;
            if (i < NV) s += src[i];
        }
        #pragma unroll
        for (int off = 32; off > 0; off >>= 1) s += __shfl_xor(s, off);
        __shared__ int ws4[4];
        if ((t & 63) == 0) ws4[t >> 6] = s;
        __syncthreads();
        if (t == 0) dst[p] = ws4[0] + ws4[1] + ws4[2] + ws4[3];
    } else if (bid < 1008) {
        int i = (bid - 880) * 256 + t;         // 0..32767
        w2t[i] = f2b(W2[(i & 255) * 128 + (i >> 8)]);
    } else {
        int i = (bid - 1008) * 256 + t;        // 0..8191
        wl1t[i] = f2b(Wl1[(i & 127) * 64 + (i >> 7)]);
    }
}

// ---------------- ptr scan (49 blocks x 1024): dual scan (train + test) ----------------

__global__ __launch_bounds__(1024) void ptr_kernel(
    const int* __restrict__ deg, const int* __restrict__ partials,
    const int* __restrict__ tdeg, const int* __restrict__ tpartials,
    int* __restrict__ ptr, int* __restrict__ cursor,
    int* __restrict__ tcursor, float* __restrict__ dinv)
{
    int b = blockIdx.x, t = threadIdx.x;
    int i = b * 1024 + t;
    int d = (i < NV) ? deg[i] : 0;
    int td = (i < NV) ? tdeg[i] : 0;
    int lane = t & 63, w = t >> 6;
    int v = d, tv = td;
    #pragma unroll
    for (int off = 1; off < 64; off <<= 1) {
        int u = __shfl_up(v, off);
        int tu = __shfl_up(tv, off);
        if (lane >= off) { v += u; tv += tu; }
    }
    __shared__ int wsum[16], woff[16], twsum[16], twoff[16];
    if (lane == 63) { wsum[w] = v; twsum[w] = tv; }
    __syncthreads();
    if (t == 0) {
        int s = 0, ts = 0;
        for (int k = 0; k < b; ++k) { s += partials[k]; ts += tpartials[k]; }
        for (int k = 0; k < 16; ++k) {
            woff[k] = s;  s += wsum[k];
            twoff[k] = ts; ts += twsum[k];
        }
    }
    __syncthreads();
    int excl = woff[w] + v - d;
    int texcl = twoff[w] + tv - td;
    if (i < NV) {
        ptr[i] = excl;
        cursor[i] = excl;
        tcursor[i] = texcl;
        dinv[i] = rsqrtf((float)d + 2.0f);   // SELF_LOOP_W = 2
        if (i == NV - 1) ptr[NV] = excl + d;
    }
}

// ---------------- fill: edat (0..3124) + eab/eorig sorted by a (3125..4687) ----------------

__global__ void fill_kernel(const int* __restrict__ tei,
                            const int* __restrict__ pos, const int* __restrict__ neg,
                            const float* __restrict__ dinv,
                            int* __restrict__ cursor, int2* __restrict__ edat,
                            int* __restrict__ tcursor, int2* __restrict__ eab,
                            int* __restrict__ eorig) {
    int bid = blockIdx.x;
    int t = threadIdx.x;
    if (bid < 3125) {
        int e = bid * 256 + t;
        if (e < ETR) {
            int row = tei[e];
            int col = tei[ETR + e];
            int p = atomicAdd(&cursor[col], 1);
            edat[p] = make_int2(row, __float_as_int(dinv[row] * dinv[col]));
        }
    } else {
        int e = (bid - 3125) * 256 + t;
        if (e < ETEST) {
            int a, b;
            if (e < EPOS) { a = pos[e]; b = pos[EPOS + e]; }
            else { int i = e - EPOS; a = neg[i]; b = neg[EPOS + i]; }
            int p = atomicAdd(&tcursor[a], 1);
            eab[p] = make_int2(a, b);
            eorig[p] = e;
        }
    }
}

// ---------------- gemm wrappers ----------------

__global__ __launch_bounds__(256) void gemm2_kernel(
    const unsigned short* __restrict__ A, const unsigned short* __restrict__ Bt,
    unsigned short* __restrict__ C)
{
    gemm_body<128, 256, false>(A, Bt, C, NV, blockIdx.x * 128, 0);
}

// ---------------- gather (bf16 in/out), 8-way edge unroll + NT stores ----------------

template<int F, bool RELU>
__global__ __launch_bounds__(256) void gather_kernel(
    const int* __restrict__ ptr, const int2* __restrict__ edat,
    const float* __restrict__ dinv, const unsigned short* __restrict__ hlin,
    const float* __restrict__ bias, unsigned short* __restrict__ hout)
{
    constexpr int V = F / 64;
    int gid = blockIdx.x * blockDim.x + threadIdx.x;
    int node = gid >> 6, lane = gid & 63;
    if (node >= NV) return;
    float dc = dinv[node];
    int j0 = ptr[node], j1 = ptr[node + 1];
    float acc[V] = {};
    const unsigned short* hb = hlin + lane * V;
    const long long* edl = (const long long*)edat;

    int j = j0;
    for (; j + 7 < j1; j += 8) {
        long long e[8];
        #pragma unroll
        for (int u = 0; u < 8; ++u) e[u] = __builtin_nontemporal_load(edl + j + u);
        if constexpr (V == 4) {
            uint2 q[8];
            #pragma unroll
            for (int u = 0; u < 8; ++u)
                q[u] = *(const uint2*)(hb + (size_t)(int)e[u] * F);
            #pragma unroll
            for (int u = 0; u < 8; ++u) {
                float n = __int_as_float((int)(e[u] >> 32));
                acc[0] += n * blo(q[u].x);
                acc[1] += n * bhi(q[u].x);
                acc[2] += n * blo(q[u].y);
                acc[3] += n * bhi(q[u].y);
            }
        } else {
            unsigned q[8];
            #pragma unroll
            for (int u = 0; u < 8; ++u)
                q[u] = *(const unsigned*)(hb + (size_t)(int)e[u] * F);
            #pragma unroll
            for (int u = 0; u < 8; ++u) {
                float n = __int_as_float((int)(e[u] >> 32));
                acc[0] += n * blo(q[u]);
                acc[1] += n * bhi(q[u]);
            }
        }
    }
    for (; j + 3 < j1; j += 4) {
        long long e[4];
        #pragma unroll
        for (int u = 0; u < 4; ++u) e[u] = __builtin_nontemporal_load(edl + j + u);
        if constexpr (V == 4) {
            uint2 q[4];
            #pragma unroll
            for (int u = 0; u < 4; ++u)
                q[u] = *(const uint2*)(hb + (size_t)(int)e[u] * F);
            #pragma unroll
            for (int u = 0; u < 4; ++u) {
                float n = __int_as_float((int)(e[u] >> 32));
                acc[0] += n * blo(q[u].x);
                acc[1] += n * bhi(q[u].x);
                acc[2] += n * blo(q[u].y);
                acc[3] += n * bhi(q[u].y);
            }
        } else {
            unsigned q[4];
            #pragma unroll
            for (int u = 0; u < 4; ++u)
                q[u] = *(const unsigned*)(hb + (size_t)(int)e[u] * F);
            #pragma unroll
            for (int u = 0; u < 4; ++u) {
                float n = __int_as_float((int)(e[u] >> 32));
                acc[0] += n * blo(q[u]);
                acc[1] += n * bhi(q[u]);
            }
        }
    }
    for (; j < j1; ++j) {
        long long e0 = __builtin_nontemporal_load(edl + j);
        float n0 = __int_as_float((int)(e0 >> 32));
        if constexpr (V == 4) {
            uint2 q0 = *(const uint2*)(hb + (size_t)(int)e0 * F);
            acc[0] += n0 * blo(q0.x);
            acc[1] += n0 * bhi(q0.x);
            acc[2] += n0 * blo(q0.y);
            acc[3] += n0 * bhi(q0.y);
        } else {
            unsigned q0 = *(const unsigned*)(hb + (size_t)(int)e0 * F);
            acc[0] += n0 * blo(q0);
            acc[1] += n0 * bhi(q0);
        }
    }

    const unsigned short* ps = hb + (size_t)node * F;
    float sw = 2.0f * dc * dc;
    if constexpr (V == 4) {
        uint2 qs = *(const uint2*)ps;
        float o0 = acc[0] + sw * blo(qs.x) + bias[lane * 4 + 0];
        float o1 = acc[1] + sw * bhi(qs.x) + bias[lane * 4 + 1];
        float o2 = acc[2] + sw * blo(qs.y) + bias[lane * 4 + 2];
        float o3 = acc[3] + sw * bhi(qs.y) + bias[lane * 4 + 3];
        if (RELU) {
            o0 = fmaxf(o0, 0.f); o1 = fmaxf(o1, 0.f);
            o2 = fmaxf(o2, 0.f); o3 = fmaxf(o3, 0.f);
        }
        union { unsigned short u[4]; unsigned long long ll; } pk;
        pk.u[0] = f2b(o0); pk.u[1] = f2b(o1); pk.u[2] = f2b(o2); pk.u[3] = f2b(o3);
        __builtin_nontemporal_store(pk.ll, (unsigned long long*)(hout + (size_t)node * F + lane * 4));
    } else {
        unsigned qs = *(const unsigned*)ps;
        float o0 = acc[0] + sw * blo(qs) + bias[lane * 2 + 0];
        float o1 = acc[1] + sw * bhi(qs) + bias[lane * 2 + 1];
        if (RELU) { o0 = fmaxf(o0, 0.f); o1 = fmaxf(o1, 0.f); }
        union { unsigned short u[2]; unsigned q; } pk;
        pk.u[0] = f2b(o0); pk.u[1] = f2b(o1);
        __builtin_nontemporal_store(pk.q, (unsigned*)(hout + (size_t)node * F + lane * 2));
    }
}

// ---------------- edge MLP via MFMA (a-sorted edges, scattered out) ----------------

__global__ __launch_bounds__(256) void edge_mlp_mfma_kernel(
    const int2* __restrict__ eab, const int* __restrict__ eorig,
    const unsigned short* __restrict__ h2, const unsigned short* __restrict__ Wl1t,
    const float* __restrict__ bl1, const float* __restrict__ Wl2,
    const float* __restrict__ bl2, float* __restrict__ out)
{
    __shared__ unsigned short Es[128][128];
    __shared__ unsigned short Ws[64][128];
    int tid = threadIdx.x;
    int lane = tid & 63, w = tid >> 6;
    int fr = lane & 15, g = lane >> 4;
    int e0 = blockIdx.x * 128;

    #pragma unroll
    for (int k = 0; k < 4; ++k) {
        int chunk = tid + k * 256;
        int row = chunk >> 4, c = chunk & 15;
        *(ushortx8*)&Ws[row][(c ^ (row & 7)) * 8] = *(const ushortx8*)&Wl1t[chunk * 8];
    }

    int et = tid >> 1, hh = tid & 1;
    int2 ab = eab[e0 + et];          // sorted by a: consecutive edges share a-rows (L2 hits)
    const unsigned short* pa = h2 + (size_t)ab.x * 128 + hh * 64;
    const unsigned short* pb = h2 + (size_t)ab.y * 128 + hh * 64;
    #pragma unroll
    for (int c8 = 0; c8 < 8; ++c8) {
        ushortx8 va = *(const ushortx8*)&pa[c8 * 8];
        ushortx8 vb = *(const ushortx8*)&pb[c8 * 8];
        ushortx8 vs = bf16add8(va, vb);
        int c = hh * 8 + c8;
        *(ushortx8*)&Es[et][(c ^ (et & 7)) * 8] = vs;
    }
    __syncthreads();

    f32x4 acc[2][4] = {};
    #pragma unroll
    for (int ks = 0; ks < 4; ++ks) {
        int c = ks * 4 + g;
        bf16x8 af[2], bfr[4];
        #pragma unroll
        for (int m = 0; m < 2; ++m) {
            int r = w * 32 + m * 16 + fr;
            af[m] = *(const bf16x8*)&Es[r][(c ^ (r & 7)) * 8];
        }
        #pragma unroll
        for (int n = 0; n < 4; ++n) {
            int r = n * 16 + fr;
            bfr[n] = *(const bf16x8*)&Ws[r][(c ^ (r & 7)) * 8];
        }
        #pragma unroll
        for (int m = 0; m < 2; ++m)
            #pragma unroll
            for (int n = 0; n < 4; ++n)
                acc[m][n] = __builtin_amdgcn_mfma_f32_16x16x32_bf16(af[m], bfr[n], acc[m][n], 0, 0, 0);
    }

    float bl2v = bl2[0];
    float b1v[4], w2v[4];
    #pragma unroll
    for (int n = 0; n < 4; ++n) {
        b1v[n] = bl1[n * 16 + fr];
        w2v[n] = Wl2[n * 16 + fr];
    }
    #pragma unroll
    for (int m = 0; m < 2; ++m) {
        float p[4];
        #pragma unroll
        for (int j = 0; j < 4; ++j) {
            float s = 0.f;
            #pragma unroll
            for (int n = 0; n < 4; ++n)
                s += fmaxf(acc[m][n][j] + b1v[n], 0.0f) * w2v[n];
            p[j] = s;
        }
        #pragma unroll
        for (int off = 1; off < 16; off <<= 1) {
            #pragma unroll
            for (int j = 0; j < 4; ++j)
                p[j] += __shfl_xor(p[j], off);
        }
        int ebase = e0 + w * 32 + m * 16 + g * 4;
        #pragma unroll
        for (int j = 0; j < 4; ++j)
            if (fr == j)
                out[eorig[ebase + j]] = 1.0f / (1.0f + expf(-(p[j] + bl2v)));
    }
}

// ---------------- launch ----------------

extern "C" void kernel_launch(void* const* d_in, const int* in_sizes, int n_in,
                              void* d_out, int out_size, void* d_ws, size_t ws_size,
                              hipStream_t stream) {
    const float* x   = (const float*)d_in[0];
    const int*   tei = (const int*)d_in[1];
    const int*   pos = (const int*)d_in[2];
    const int*   neg = (const int*)d_in[3];
    const float* W1  = (const float*)d_in[4];
    const float* b1  = (const float*)d_in[5];
    const float* W2  = (const float*)d_in[6];
    const float* b2  = (const float*)d_in[7];
    const float* Wl1 = (const float*)d_in[8];
    const float* bl1 = (const float*)d_in[9];
    const float* Wl2 = (const float*)d_in[10];
    const float* bl2 = (const float*)d_in[11];
    float* out = (float*)d_out;

    // workspace layout (4B-word offsets)
    float* fws = (float*)d_ws;
    int*   iws = (int*)d_ws;
    unsigned short* usws = (unsigned short*)d_ws;
    float* dinv      = fws;                       // [50000]
    int*   deg       = iws + 50000;               // [50000]  \ zeroed together
    int*   tdeg      = iws + 100000;              // [50000]  /
    int*   ptr       = iws + 150064;              // [50001]
    int*   cursor    = iws + 200128;              // [50000]
    int*   tcursor   = iws + 250128;              // [50000]
    int*   partials  = iws + 300160;              // [64]
    int*   tpartials = iws + 300224;              // [64]
    int2*  edat      = (int2*)(iws + 300288);     // [800000] -> ends 1900288
    int2*  eab       = (int2*)(iws + 1900288);    // [400000] -> ends 2700288
    int*   eorig     = iws + 2700288;             // [400000] -> ends 3100288
    unsigned short* w1t  = usws + 2ull * 3100288; // [65536]  -> w 3133056
    unsigned short* w2t  = usws + 2ull * 3133056; // [32768]  -> w 3149440
    unsigned short* wl1t = usws + 2ull * 3149440; // [8192]   -> w 3153536
    unsigned short* bufX   = usws + 2ull * 3153536;  // h2lin [6.4M] -> w 6353536
    unsigned short* bufL16 = usws + 2ull * 6353536;  // h1lin, then h2 [12.8M] -> w 12753536
    unsigned short* bufH   = usws + 2ull * 12753536; // h1 [12.8M] -> w 19153536

    hipMemsetAsync(deg, 0, 100000 * sizeof(int), stream);

    // fat0: both histograms + cvt(W1)
    fat0_kernel<<<4944, 256, 0, stream>>>(tei, pos, neg, deg, tdeg, W1, w1t);

    // fat1: gemm1 + partial sums (deg, tdeg) + cvt(W2, Wl1)
    fat1_kernel<<<1040, 256, 0, stream>>>(x, w1t, bufL16, deg, partials, tdeg, tpartials,
                                          W2, w2t, Wl1, wl1t);

    ptr_kernel<<<49, 1024, 0, stream>>>(deg, partials, tdeg, tpartials, ptr, cursor, tcursor, dinv);
    fill_kernel<<<4688, 256, 0, stream>>>(tei, pos, neg, dinv, cursor, edat, tcursor, eab, eorig);

    // layer 1 gather
    gather_kernel<256, true><<<(NV * 64) / 256, 256, 0, stream>>>(ptr, edat, dinv, bufL16, b1, bufH);

    // layer 2: h2lin = h1 @ w2t -> bufX; gather -> h2 (bufL16)
    gemm2_kernel<<<391, 256, 0, stream>>>(bufH, w2t, bufX);
    gather_kernel<128, false><<<(NV * 64) / 256, 256, 0, stream>>>(ptr, edat, dinv, bufX, b2, bufL16);

    // edge MLP head (MFMA, a-sorted edges)
    edge_mlp_mfma_kernel<<<ETEST / 128, 256, 0, stream>>>(eab, eorig, bufL16, wl1t, bl1, Wl2, bl2, out);
}

// Round 13
// 289.301 us; speedup vs baseline: 2.4688x; 1.1301x over previous
//
#include <hip/hip_runtime.h>
#include <math.h>

#define NV 50000
#define ETR 800000
#define EPOS 200000
#define ETEST 400000

typedef __attribute__((ext_vector_type(8))) short bf16x8;
typedef __attribute__((ext_vector_type(8))) unsigned short ushortx8;
typedef __attribute__((ext_vector_type(4))) float f32x4;

__device__ inline unsigned short f2b(float f) {
    union { float f; unsigned u; } v; v.f = f;
    unsigned r = v.u + 0x7fffu + ((v.u >> 16) & 1u);   // RNE
    return (unsigned short)(r >> 16);
}
__device__ inline float blo(unsigned q) { union { unsigned u; float f; } v; v.u = q << 16; return v.f; }
__device__ inline float bhi(unsigned q) { union { unsigned u; float f; } v; v.u = q & 0xffff0000u; return v.f; }
__device__ inline float b2f(unsigned short s) { union { unsigned u; float f; } v; v.u = ((unsigned)s) << 16; return v.f; }

__device__ inline ushortx8 bf16add8(ushortx8 a, ushortx8 b) {
    ushortx8 r;
    #pragma unroll
    for (int i = 0; i < 8; ++i)
        r[i] = f2b(b2f(a[i]) + b2f(b[i]));
    return r;
}

// ---------------- shared GEMM body (128x128 tile, 4 waves 2x2, BK=64, swizzled LDS) ----------------
// Epilogue: C quadrant staged in LDS (reusing the staging region), written out as
// coalesced 16B stores (vs 64 scalar ushort stores = 32B write fragments before).

template<int N, int K, bool AF32>
__device__ __forceinline__ void gemm_body(
    const void* __restrict__ Av, const unsigned short* __restrict__ Bt,
    unsigned short* __restrict__ C, int M, int row0, int col0)
{
    constexpr int BK = 64;
    __shared__ unsigned short smem[18464];   // 36.9KB: staging (32KB) then C-stage (4 x 4616)
    unsigned short (*Asm)[BK] = (unsigned short (*)[BK])smem;          // [128][64]
    unsigned short (*Bsm)[BK] = (unsigned short (*)[BK])(smem + 8192); // [128][64]
    int tid = threadIdx.x;
    int lane = tid & 63, wid = tid >> 6;
    int wr = wid >> 1, wc = wid & 1;

    int sr = tid >> 3;
    int s8 = tid & 7;
    int sswz = s8 ^ (sr & 7);
    int fr = lane & 15;
    int g  = lane >> 4;

    f32x4 acc[4][4] = {};

    for (int k0 = 0; k0 < K; k0 += BK) {
        #pragma unroll
        for (int i = 0; i < 4; ++i) {
            int r = sr + i * 32;
            int gr = row0 + r;
            ushortx8 va = {0, 0, 0, 0, 0, 0, 0, 0};
            if constexpr (AF32) {
                const float* Af = (const float*)Av;
                if (gr < M) {
                    float4 f0 = *(const float4*)&Af[(size_t)gr * K + k0 + s8 * 8];
                    float4 f1 = *(const float4*)&Af[(size_t)gr * K + k0 + s8 * 8 + 4];
                    va[0] = f2b(f0.x); va[1] = f2b(f0.y); va[2] = f2b(f0.z); va[3] = f2b(f0.w);
                    va[4] = f2b(f1.x); va[5] = f2b(f1.y); va[6] = f2b(f1.z); va[7] = f2b(f1.w);
                }
            } else {
                const unsigned short* Ab = (const unsigned short*)Av;
                if (gr < M) va = *(const ushortx8*)&Ab[(size_t)gr * K + k0 + s8 * 8];
            }
            *(ushortx8*)&Asm[r][sswz * 8] = va;
            ushortx8 vb = *(const ushortx8*)&Bt[(size_t)(col0 + r) * K + k0 + s8 * 8];
            *(ushortx8*)&Bsm[r][sswz * 8] = vb;
        }
        __syncthreads();
        #pragma unroll
        for (int kf = 0; kf < BK; kf += 32) {
            int sbase = kf >> 3;
            bf16x8 af[4], bfr[4];
            #pragma unroll
            for (int m = 0; m < 4; ++m) {
                int rr = wr * 64 + m * 16 + fr;
                af[m] = *(const bf16x8*)&Asm[rr][((sbase + g) ^ (fr & 7)) * 8];
            }
            #pragma unroll
            for (int n = 0; n < 4; ++n) {
                int rr = wc * 64 + n * 16 + fr;
                bfr[n] = *(const bf16x8*)&Bsm[rr][((sbase + g) ^ (fr & 7)) * 8];
            }
            #pragma unroll
            for (int m = 0; m < 4; ++m)
                #pragma unroll
                for (int n = 0; n < 4; ++n)
                    acc[m][n] = __builtin_amdgcn_mfma_f32_16x16x32_bf16(af[m], bfr[n], acc[m][n], 0, 0, 0);
        }
        __syncthreads();
    }

    // ---- epilogue: C/D layout col=lane&15, row=(lane>>4)*4+j ; LDS-staged store ----
    {
        unsigned short* cw = smem + wid * 4616;   // per-wave [64][72] + skew
        #pragma unroll
        for (int m = 0; m < 4; ++m)
            #pragma unroll
            for (int n = 0; n < 4; ++n)
                #pragma unroll
                for (int j = 0; j < 4; ++j)
                    cw[(m * 16 + g * 4 + j) * 72 + n * 16 + fr] = f2b(acc[m][n][j]);
        __syncthreads();
        int row = tid >> 1;                   // 0..127
        int half = tid & 1;                   // col quadrant
        int q = ((row >> 6) << 1) + half;     // owning wave quadrant
        int rl = row & 63;
        const unsigned short* cr = smem + q * 4616 + rl * 72;
        int gr = row0 + row;
        if (gr < M) {
            unsigned short* gp = C + (size_t)gr * N + col0 + half * 64;
            #pragma unroll
            for (int c8 = 0; c8 < 8; ++c8)
                *(ushortx8*)&gp[c8 * 8] = *(const ushortx8*)&cr[c8 * 8];
        }
    }
}

// ---------------- fat0: deg histogram (blocks 0..3124) + cvt W1 (3125..3380) ----------------

__global__ __launch_bounds__(256) void fat0_kernel(
    const int* __restrict__ tei, int* __restrict__ deg,
    const float* __restrict__ W1, unsigned short* __restrict__ w1t)
{
    int bid = blockIdx.x;
    int t = threadIdx.x;
    if (bid < 3125) {
        int e = bid * 256 + t;
        if (e < ETR) atomicAdd(&deg[tei[ETR + e]], 1);
    } else {
        int i = (bid - 3125) * 256 + t;        // 0..65535
        w1t[i] = f2b(W1[(i & 255) * 256 + (i >> 8)]);
    }
}

// ---------------- fat1: gemm1 (0..781) + partials (782..830) + cvt W2 (831..958) + cvt Wl1 (959..990) ----------------

__global__ __launch_bounds__(256) void fat1_kernel(
    const float* __restrict__ x, const unsigned short* __restrict__ w1t,
    unsigned short* __restrict__ h1lin,
    const int* __restrict__ deg, int* __restrict__ partials,
    const float* __restrict__ W2, unsigned short* __restrict__ w2t,
    const float* __restrict__ Wl1, unsigned short* __restrict__ wl1t)
{
    int bid = blockIdx.x;
    int t = threadIdx.x;
    if (bid < 782) {
        // adjacent blocks share the A row-panel (L2 reuse)
        int row0 = (bid >> 1) * 128, col0 = (bid & 1) * 128;
        gemm_body<256, 256, true>(x, w1t, h1lin, NV, row0, col0);
    } else if (bid < 831) {
        int p = bid - 782;
        int base = p * 1024;
        int s = 0;
        #pragma unroll
        for (int k = 0; k < 4; ++k) {
            int i = base + t + k * 256;
            if (i < NV) s += deg[i];
        }
        #pragma unroll
        for (int off = 32; off > 0; off >>= 1) s += __shfl_xor(s, off);
        __shared__ int ws4[4];
        if ((t & 63) == 0) ws4[t >> 6] = s;
        __syncthreads();
        if (t == 0) partials[p] = ws4[0] + ws4[1] + ws4[2] + ws4[3];
    } else if (bid < 959) {
        int i = (bid - 831) * 256 + t;         // 0..32767
        w2t[i] = f2b(W2[(i & 255) * 128 + (i >> 8)]);
    } else {
        int i = (bid - 959) * 256 + t;         // 0..8191
        wl1t[i] = f2b(Wl1[(i & 127) * 64 + (i >> 7)]);
    }
}

// ---------------- ptr scan (49 blocks x 1024) ----------------

__global__ __launch_bounds__(1024) void ptr_kernel(
    const int* __restrict__ deg, const int* __restrict__ partials,
    int* __restrict__ ptr, int* __restrict__ cursor, float* __restrict__ dinv)
{
    int b = blockIdx.x, t = threadIdx.x;
    int i = b * 1024 + t;
    int d = (i < NV) ? deg[i] : 0;
    int lane = t & 63, w = t >> 6;
    int v = d;
    #pragma unroll
    for (int off = 1; off < 64; off <<= 1) {
        int u = __shfl_up(v, off);
        if (lane >= off) v += u;
    }
    __shared__ int wsum[16], woff[16];
    if (lane == 63) wsum[w] = v;
    __syncthreads();
    if (t == 0) {
        int s = 0;
        for (int k = 0; k < b; ++k) s += partials[k];
        for (int k = 0; k < 16; ++k) { woff[k] = s; s += wsum[k]; }
    }
    __syncthreads();
    int excl = woff[w] + v - d;
    if (i < NV) {
        ptr[i] = excl;
        cursor[i] = excl;
        dinv[i] = rsqrtf((float)d + 2.0f);   // SELF_LOOP_W = 2
        if (i == NV - 1) ptr[NV] = excl + d;
    }
}

// edat[p] = (source row, norm = dinv[row]*dinv[col])
__global__ void fill_kernel(const int* __restrict__ tei, const float* __restrict__ dinv,
                            int* __restrict__ cursor, int2* __restrict__ edat) {
    int e = blockIdx.x * blockDim.x + threadIdx.x;
    if (e < ETR) {
        int row = tei[e];
        int col = tei[ETR + e];
        int p = atomicAdd(&cursor[col], 1);
        edat[p] = make_int2(row, __float_as_int(dinv[row] * dinv[col]));
    }
}

// ---------------- gemm2 wrapper ----------------

__global__ __launch_bounds__(256) void gemm2_kernel(
    const unsigned short* __restrict__ A, const unsigned short* __restrict__ Bt,
    unsigned short* __restrict__ C)
{
    gemm_body<128, 256, false>(A, Bt, C, NV, blockIdx.x * 128, 0);
}

// ---------------- gather (bf16 in/out), 8-way edge unroll + NT stores ----------------

template<int F, bool RELU>
__global__ __launch_bounds__(256) void gather_kernel(
    const int* __restrict__ ptr, const int2* __restrict__ edat,
    const float* __restrict__ dinv, const unsigned short* __restrict__ hlin,
    const float* __restrict__ bias, unsigned short* __restrict__ hout)
{
    constexpr int V = F / 64;
    int gid = blockIdx.x * blockDim.x + threadIdx.x;
    int node = gid >> 6, lane = gid & 63;
    if (node >= NV) return;
    float dc = dinv[node];
    int j0 = ptr[node], j1 = ptr[node + 1];
    float acc[V] = {};
    const unsigned short* hb = hlin + lane * V;
    const long long* edl = (const long long*)edat;

    int j = j0;
    for (; j + 7 < j1; j += 8) {
        long long e[8];
        #pragma unroll
        for (int u = 0; u < 8; ++u) e[u] = __builtin_nontemporal_load(edl + j + u);
        if constexpr (V == 4) {
            uint2 q[8];
            #pragma unroll
            for (int u = 0; u < 8; ++u)
                q[u] = *(const uint2*)(hb + (size_t)(int)e[u] * F);
            #pragma unroll
            for (int u = 0; u < 8; ++u) {
                float n = __int_as_float((int)(e[u] >> 32));
                acc[0] += n * blo(q[u].x);
                acc[1] += n * bhi(q[u].x);
                acc[2] += n * blo(q[u].y);
                acc[3] += n * bhi(q[u].y);
            }
        } else {
            unsigned q[8];
            #pragma unroll
            for (int u = 0; u < 8; ++u)
                q[u] = *(const unsigned*)(hb + (size_t)(int)e[u] * F);
            #pragma unroll
            for (int u = 0; u < 8; ++u) {
                float n = __int_as_float((int)(e[u] >> 32));
                acc[0] += n * blo(q[u]);
                acc[1] += n * bhi(q[u]);
            }
        }
    }
    for (; j + 3 < j1; j += 4) {
        long long e[4];
        #pragma unroll
        for (int u = 0; u < 4; ++u) e[u] = __builtin_nontemporal_load(edl + j + u);
        if constexpr (V == 4) {
            uint2 q[4];
            #pragma unroll
            for (int u = 0; u < 4; ++u)
                q[u] = *(const uint2*)(hb + (size_t)(int)e[u] * F);
            #pragma unroll
            for (int u = 0; u < 4; ++u) {
                float n = __int_as_float((int)(e[u] >> 32));
                acc[0] += n * blo(q[u].x);
                acc[1] += n * bhi(q[u].x);
                acc[2] += n * blo(q[u].y);
                acc[3] += n * bhi(q[u].y);
            }
        } else {
            unsigned q[4];
            #pragma unroll
            for (int u = 0; u < 4; ++u)
                q[u] = *(const unsigned*)(hb + (size_t)(int)e[u] * F);
            #pragma unroll
            for (int u = 0; u < 4; ++u) {
                float n = __int_as_float((int)(e[u] >> 32));
                acc[0] += n * blo(q[u]);
                acc[1] += n * bhi(q[u]);
            }
        }
    }
    for (; j < j1; ++j) {
        long long e0 = __builtin_nontemporal_load(edl + j);
        float n0 = __int_as_float((int)(e0 >> 32));
        if constexpr (V == 4) {
            uint2 q0 = *(const uint2*)(hb + (size_t)(int)e0 * F);
            acc[0] += n0 * blo(q0.x);
            acc[1] += n0 * bhi(q0.x);
            acc[2] += n0 * blo(q0.y);
            acc[3] += n0 * bhi(q0.y);
        } else {
            unsigned q0 = *(const unsigned*)(hb + (size_t)(int)e0 * F);
            acc[0] += n0 * blo(q0);
            acc[1] += n0 * bhi(q0);
        }
    }

    const unsigned short* ps = hb + (size_t)node * F;
    float sw = 2.0f * dc * dc;
    if constexpr (V == 4) {
        uint2 qs = *(const uint2*)ps;
        float o0 = acc[0] + sw * blo(qs.x) + bias[lane * 4 + 0];
        float o1 = acc[1] + sw * bhi(qs.x) + bias[lane * 4 + 1];
        float o2 = acc[2] + sw * blo(qs.y) + bias[lane * 4 + 2];
        float o3 = acc[3] + sw * bhi(qs.y) + bias[lane * 4 + 3];
        if (RELU) {
            o0 = fmaxf(o0, 0.f); o1 = fmaxf(o1, 0.f);
            o2 = fmaxf(o2, 0.f); o3 = fmaxf(o3, 0.f);
        }
        union { unsigned short u[4]; unsigned long long ll; } pk;
        pk.u[0] = f2b(o0); pk.u[1] = f2b(o1); pk.u[2] = f2b(o2); pk.u[3] = f2b(o3);
        __builtin_nontemporal_store(pk.ll, (unsigned long long*)(hout + (size_t)node * F + lane * 4));
    } else {
        unsigned qs = *(const unsigned*)ps;
        float o0 = acc[0] + sw * blo(qs) + bias[lane * 2 + 0];
        float o1 = acc[1] + sw * bhi(qs) + bias[lane * 2 + 1];
        if (RELU) { o0 = fmaxf(o0, 0.f); o1 = fmaxf(o1, 0.f); }
        union { unsigned short u[2]; unsigned q; } pk;
        pk.u[0] = f2b(o0); pk.u[1] = f2b(o1);
        __builtin_nontemporal_store(pk.q, (unsigned*)(hout + (size_t)node * F + lane * 2));
    }
}

// ---------------- edge MLP via MFMA ----------------

__global__ __launch_bounds__(256) void edge_mlp_mfma_kernel(
    const int* __restrict__ pos, const int* __restrict__ neg,
    const unsigned short* __restrict__ h2, const unsigned short* __restrict__ Wl1t,
    const float* __restrict__ bl1, const float* __restrict__ Wl2,
    const float* __restrict__ bl2, float* __restrict__ out)
{
    __shared__ unsigned short Es[128][128];
    __shared__ unsigned short Ws[64][128];
    int tid = threadIdx.x;
    int lane = tid & 63, w = tid >> 6;
    int fr = lane & 15, g = lane >> 4;
    int e0 = blockIdx.x * 128;

    #pragma unroll
    for (int k = 0; k < 4; ++k) {
        int chunk = tid + k * 256;
        int row = chunk >> 4, c = chunk & 15;
        *(ushortx8*)&Ws[row][(c ^ (row & 7)) * 8] = *(const ushortx8*)&Wl1t[chunk * 8];
    }

    int et = tid >> 1, hh = tid & 1;
    int eg = e0 + et;
    int a, b;
    if (eg < EPOS) { a = pos[eg]; b = pos[EPOS + eg]; }
    else { int i = eg - EPOS; a = neg[i]; b = neg[EPOS + i]; }
    const unsigned short* pa = h2 + (size_t)a * 128 + hh * 64;
    const unsigned short* pb = h2 + (size_t)b * 128 + hh * 64;
    #pragma unroll
    for (int c8 = 0; c8 < 8; ++c8) {
        ushortx8 va = *(const ushortx8*)&pa[c8 * 8];
        ushortx8 vb = *(const ushortx8*)&pb[c8 * 8];
        ushortx8 vs = bf16add8(va, vb);
        int c = hh * 8 + c8;
        *(ushortx8*)&Es[et][(c ^ (et & 7)) * 8] = vs;
    }
    __syncthreads();

    f32x4 acc[2][4] = {};
    #pragma unroll
    for (int ks = 0; ks < 4; ++ks) {
        int c = ks * 4 + g;
        bf16x8 af[2], bfr[4];
        #pragma unroll
        for (int m = 0; m < 2; ++m) {
            int r = w * 32 + m * 16 + fr;
            af[m] = *(const bf16x8*)&Es[r][(c ^ (r & 7)) * 8];
        }
        #pragma unroll
        for (int n = 0; n < 4; ++n) {
            int r = n * 16 + fr;
            bfr[n] = *(const bf16x8*)&Ws[r][(c ^ (r & 7)) * 8];
        }
        #pragma unroll
        for (int m = 0; m < 2; ++m)
            #pragma unroll
            for (int n = 0; n < 4; ++n)
                acc[m][n] = __builtin_amdgcn_mfma_f32_16x16x32_bf16(af[m], bfr[n], acc[m][n], 0, 0, 0);
    }

    float bl2v = bl2[0];
    float b1v[4], w2v[4];
    #pragma unroll
    for (int n = 0; n < 4; ++n) {
        b1v[n] = bl1[n * 16 + fr];
        w2v[n] = Wl2[n * 16 + fr];
    }
    #pragma unroll
    for (int m = 0; m < 2; ++m) {
        float p[4];
        #pragma unroll
        for (int j = 0; j < 4; ++j) {
            float s = 0.f;
            #pragma unroll
            for (int n = 0; n < 4; ++n)
                s += fmaxf(acc[m][n][j] + b1v[n], 0.0f) * w2v[n];
            p[j] = s;
        }
        #pragma unroll
        for (int off = 1; off < 16; off <<= 1) {
            #pragma unroll
            for (int j = 0; j < 4; ++j)
                p[j] += __shfl_xor(p[j], off);
        }
        int ebase = e0 + w * 32 + m * 16 + g * 4;
        #pragma unroll
        for (int j = 0; j < 4; ++j)
            if (fr == j)
                out[ebase + j] = 1.0f / (1.0f + expf(-(p[j] + bl2v)));
    }
}

// ---------------- launch ----------------

extern "C" void kernel_launch(void* const* d_in, const int* in_sizes, int n_in,
                              void* d_out, int out_size, void* d_ws, size_t ws_size,
                              hipStream_t stream) {
    const float* x   = (const float*)d_in[0];
    const int*   tei = (const int*)d_in[1];
    const int*   pos = (const int*)d_in[2];
    const int*   neg = (const int*)d_in[3];
    const float* W1  = (const float*)d_in[4];
    const float* b1  = (const float*)d_in[5];
    const float* W2  = (const float*)d_in[6];
    const float* b2  = (const float*)d_in[7];
    const float* Wl1 = (const float*)d_in[8];
    const float* bl1 = (const float*)d_in[9];
    const float* Wl2 = (const float*)d_in[10];
    const float* bl2 = (const float*)d_in[11];
    float* out = (float*)d_out;

    // workspace (4B-word offsets)
    float* fws = (float*)d_ws;
    int*   iws = (int*)d_ws;
    unsigned short* usws = (unsigned short*)d_ws;
    float* dinv     = fws;                         // [50000]
    int*   deg      = iws + 50000;                 // [50000]
    int*   ptr      = iws + 100000;                // [50001]
    int*   cursor   = iws + 150002;                // [50000]
    int2*  edat     = (int2*)(iws + 200064);       // [800000] int2 -> ends 1800064
    int*   partials = iws + 1800064;               // [64]
    unsigned short* w1t  = usws + 2ull * 1800192;  // [65536]
    unsigned short* w2t  = usws + 2ull * 1832960;  // [32768]
    unsigned short* wl1t = usws + 2ull * 1849344;  // [8192]
    unsigned short* bufX = usws + 2ull * 1853504;  // h2lin bf16
    unsigned short* bufL16 = usws + 2ull * 8253504;  // h1lin bf16, then h2 bf16
    unsigned short* bufH = usws + 2ull * 14653504;   // h1 bf16

    hipMemsetAsync(deg, 0, NV * sizeof(int), stream);

    // fat0: deg histogram + cvt(W1)
    fat0_kernel<<<3381, 256, 0, stream>>>(tei, deg, W1, w1t);

    // fat1: gemm1 (h1lin = bf16(x) @ w1t) + partial sums + cvt(W2, Wl1)
    fat1_kernel<<<991, 256, 0, stream>>>(x, w1t, bufL16, deg, partials, W2, w2t, Wl1, wl1t);

    ptr_kernel<<<49, 1024, 0, stream>>>(deg, partials, ptr, cursor, dinv);
    fill_kernel<<<(ETR + 255) / 256, 256, 0, stream>>>(tei, dinv, cursor, edat);

    // layer 1 gather
    gather_kernel<256, true><<<(NV * 64) / 256, 256, 0, stream>>>(ptr, edat, dinv, bufL16, b1, bufH);

    // layer 2: h2lin = h1 @ w2t -> bufX; gather -> h2 (bufL16)
    gemm2_kernel<<<391, 256, 0, stream>>>(bufH, w2t, bufX);
    gather_kernel<128, false><<<(NV * 64) / 256, 256, 0, stream>>>(ptr, edat, dinv, bufX, b2, bufL16);

    // edge MLP head (MFMA)
    edge_mlp_mfma_kernel<<<ETEST / 128, 256, 0, stream>>>(pos, neg, bufL16, wl1t, bl1, Wl2, bl2, out);
}

// Round 14
// 281.288 us; speedup vs baseline: 2.5392x; 1.0285x over previous
//
#include <hip/hip_runtime.h>
#include <math.h>

#define NV 50000
#define ETR 800000
#define EPOS 200000
#define ETEST 400000

typedef __attribute__((ext_vector_type(8))) short bf16x8;
typedef __attribute__((ext_vector_type(8))) unsigned short ushortx8;
typedef __attribute__((ext_vector_type(4))) float f32x4;

__device__ inline unsigned short f2b(float f) {
    union { float f; unsigned u; } v; v.f = f;
    unsigned r = v.u + 0x7fffu + ((v.u >> 16) & 1u);   // RNE
    return (unsigned short)(r >> 16);
}
__device__ inline float blo(unsigned q) { union { unsigned u; float f; } v; v.u = q << 16; return v.f; }
__device__ inline float bhi(unsigned q) { union { unsigned u; float f; } v; v.u = q & 0xffff0000u; return v.f; }
__device__ inline float b2f(unsigned short s) { union { unsigned u; float f; } v; v.u = ((unsigned)s) << 16; return v.f; }

__device__ inline ushortx8 bf16add8(ushortx8 a, ushortx8 b) {
    ushortx8 r;
    #pragma unroll
    for (int i = 0; i < 8; ++i)
        r[i] = f2b(b2f(a[i]) + b2f(b[i]));
    return r;
}

// direct-to-LDS 16B load (linear LDS dest; swizzle applied on the GLOBAL side)
#define GLOAD_LDS16(g, l) __builtin_amdgcn_global_load_lds( \
    (__attribute__((address_space(1))) void*)(g), \
    (__attribute__((address_space(3))) void*)(l), 16, 0, 0)

// ---------------- shared GEMM body (128x128 tile, 4 waves 2x2, BK=64) ----------------
// Staging: Bt (and A when bf16) via global_load_lds with pre-swizzled global source
// chunk (s8^(r&7)) and LINEAR LDS dest -> LDS content identical to the old
// swizzled-write layout, so the fragment-read path is unchanged (rule #21).
// Epilogue: C quadrant staged in LDS, written as coalesced 16B stores.

template<int N, int K, bool AF32>
__device__ __forceinline__ void gemm_body(
    const void* __restrict__ Av, const unsigned short* __restrict__ Bt,
    unsigned short* __restrict__ C, int M, int row0, int col0)
{
    constexpr int BK = 64;
    __shared__ unsigned short smem[18464];   // staging 32KB, then C-stage 4 x 4616
    unsigned short (*Asm)[BK] = (unsigned short (*)[BK])smem;          // [128][64]
    unsigned short (*Bsm)[BK] = (unsigned short (*)[BK])(smem + 8192); // [128][64]
    int tid = threadIdx.x;
    int lane = tid & 63, wid = tid >> 6;
    int wr = wid >> 1, wc = wid & 1;

    int sr = tid >> 3;                 // 0..31
    int s8 = tid & 7;                  // linear 16B slot (LDS dest)
    int fr = lane & 15;
    int g  = lane >> 4;

    f32x4 acc[4][4] = {};

    for (int k0 = 0; k0 < K; k0 += BK) {
        #pragma unroll
        for (int i = 0; i < 4; ++i) {
            int r = sr + i * 32;
            int gr = row0 + r;
            int s8sw = s8 ^ (r & 7);   // pre-swizzled global chunk (involution)
            GLOAD_LDS16(&Bt[(size_t)(col0 + r) * K + k0 + s8sw * 8], &Bsm[r][s8 * 8]);
            if constexpr (AF32) {
                const float* Af = (const float*)Av;
                ushortx8 va = {0, 0, 0, 0, 0, 0, 0, 0};
                if (gr < M) {
                    float4 f0 = *(const float4*)&Af[(size_t)gr * K + k0 + s8 * 8];
                    float4 f1 = *(const float4*)&Af[(size_t)gr * K + k0 + s8 * 8 + 4];
                    va[0] = f2b(f0.x); va[1] = f2b(f0.y); va[2] = f2b(f0.z); va[3] = f2b(f0.w);
                    va[4] = f2b(f1.x); va[5] = f2b(f1.y); va[6] = f2b(f1.z); va[7] = f2b(f1.w);
                }
                *(ushortx8*)&Asm[r][(s8 ^ (r & 7)) * 8] = va;   // swizzled write (same content)
            } else {
                const unsigned short* Ab = (const unsigned short*)Av;
                GLOAD_LDS16(&Ab[(size_t)gr * K + k0 + s8sw * 8], &Asm[r][s8 * 8]);
            }
        }
        __syncthreads();
        #pragma unroll
        for (int kf = 0; kf < BK; kf += 32) {
            int sbase = kf >> 3;
            bf16x8 af[4], bfr[4];
            #pragma unroll
            for (int m = 0; m < 4; ++m) {
                int rr = wr * 64 + m * 16 + fr;
                af[m] = *(const bf16x8*)&Asm[rr][((sbase + g) ^ (fr & 7)) * 8];
            }
            #pragma unroll
            for (int n = 0; n < 4; ++n) {
                int rr = wc * 64 + n * 16 + fr;
                bfr[n] = *(const bf16x8*)&Bsm[rr][((sbase + g) ^ (fr & 7)) * 8];
            }
            #pragma unroll
            for (int m = 0; m < 4; ++m)
                #pragma unroll
                for (int n = 0; n < 4; ++n)
                    acc[m][n] = __builtin_amdgcn_mfma_f32_16x16x32_bf16(af[m], bfr[n], acc[m][n], 0, 0, 0);
        }
        __syncthreads();
    }

    // ---- epilogue: C/D layout col=lane&15, row=(lane>>4)*4+j ; LDS-staged store ----
    {
        unsigned short* cw = smem + wid * 4616;   // per-wave [64][72] + skew
        #pragma unroll
        for (int m = 0; m < 4; ++m)
            #pragma unroll
            for (int n = 0; n < 4; ++n)
                #pragma unroll
                for (int j = 0; j < 4; ++j)
                    cw[(m * 16 + g * 4 + j) * 72 + n * 16 + fr] = f2b(acc[m][n][j]);
        __syncthreads();
        int row = tid >> 1;                   // 0..127
        int half = tid & 1;                   // col quadrant
        int q = ((row >> 6) << 1) + half;     // owning wave quadrant
        int rl = row & 63;
        const unsigned short* cr = smem + q * 4616 + rl * 72;
        int gr = row0 + row;
        if (gr < M) {
            unsigned short* gp = C + (size_t)gr * N + col0 + half * 64;
            #pragma unroll
            for (int c8 = 0; c8 < 8; ++c8)
                *(ushortx8*)&gp[c8 * 8] = *(const ushortx8*)&cr[c8 * 8];
        }
    }
}

// ---------------- fat0: deg histogram (blocks 0..3124) + cvt W1 (3125..3380) ----------------

__global__ __launch_bounds__(256) void fat0_kernel(
    const int* __restrict__ tei, int* __restrict__ deg,
    const float* __restrict__ W1, unsigned short* __restrict__ w1t)
{
    int bid = blockIdx.x;
    int t = threadIdx.x;
    if (bid < 3125) {
        int e = bid * 256 + t;
        if (e < ETR) atomicAdd(&deg[tei[ETR + e]], 1);
    } else {
        int i = (bid - 3125) * 256 + t;        // 0..65535
        w1t[i] = f2b(W1[(i & 255) * 256 + (i >> 8)]);
    }
}

// ---------------- ptr2: self-sufficient scan (49 blocks x 1024) ----------------
// Each block computes its own prefix base by summing deg[0..b*1024) directly
// (<=49k ints, L2-resident) -> no separate partials pass needed.

__global__ __launch_bounds__(1024) void ptr2_kernel(
    const int* __restrict__ deg, int* __restrict__ ptr,
    int* __restrict__ cursor, float* __restrict__ dinv)
{
    int b = blockIdx.x, t = threadIdx.x;
    int lane = t & 63, w = t >> 6;
    __shared__ int wred[16], wsum[16], woff[16];
    __shared__ int base_s;

    // prefix base = sum deg[0 .. b*1024)
    int pre = 0;
    int lim = b * 1024;
    for (int i = t; i < lim; i += 1024) pre += deg[i];
    #pragma unroll
    for (int off = 32; off > 0; off >>= 1) pre += __shfl_xor(pre, off);
    if (lane == 0) wred[w] = pre;
    __syncthreads();
    if (t == 0) {
        int s = 0;
        #pragma unroll
        for (int k = 0; k < 16; ++k) s += wred[k];
        base_s = s;
    }

    // intra-block scan
    int i = b * 1024 + t;
    int d = (i < NV) ? deg[i] : 0;
    int v = d;
    #pragma unroll
    for (int off = 1; off < 64; off <<= 1) {
        int u = __shfl_up(v, off);
        if (lane >= off) v += u;
    }
    if (lane == 63) wsum[w] = v;
    __syncthreads();
    if (t == 0) {
        int s = base_s;
        #pragma unroll
        for (int k = 0; k < 16; ++k) { woff[k] = s; s += wsum[k]; }
    }
    __syncthreads();
    int excl = woff[w] + v - d;
    if (i < NV) {
        ptr[i] = excl;
        cursor[i] = excl;
        dinv[i] = rsqrtf((float)d + 2.0f);   // SELF_LOOP_W = 2
        if (i == NV - 1) ptr[NV] = excl + d;
    }
}

// ---------------- fat1: gemm1 (0..781) + fill (782..3906) + cvt W2 (3907..4034)
//                       + cvt Wl1 (4035..4066) ----------------
// fill's ~12us hides under gemm1's occupancy shadow.

__global__ __launch_bounds__(256) void fat1_kernel(
    const float* __restrict__ x, const unsigned short* __restrict__ w1t,
    unsigned short* __restrict__ h1lin,
    const int* __restrict__ tei, const float* __restrict__ dinv,
    int* __restrict__ cursor, int2* __restrict__ edat,
    const float* __restrict__ W2, unsigned short* __restrict__ w2t,
    const float* __restrict__ Wl1, unsigned short* __restrict__ wl1t)
{
    int bid = blockIdx.x;
    int t = threadIdx.x;
    if (bid < 782) {
        // adjacent blocks share the A row-panel (L2 reuse)
        int row0 = (bid >> 1) * 128, col0 = (bid & 1) * 128;
        gemm_body<256, 256, true>(x, w1t, h1lin, NV, row0, col0);
    } else if (bid < 3907) {
        int e = (bid - 782) * 256 + t;
        if (e < ETR) {
            int row = tei[e];
            int col = tei[ETR + e];
            int p = atomicAdd(&cursor[col], 1);
            edat[p] = make_int2(row, __float_as_int(dinv[row] * dinv[col]));
        }
    } else if (bid < 4035) {
        int i = (bid - 3907) * 256 + t;        // 0..32767
        w2t[i] = f2b(W2[(i & 255) * 128 + (i >> 8)]);
    } else {
        int i = (bid - 4035) * 256 + t;        // 0..8191
        wl1t[i] = f2b(Wl1[(i & 127) * 64 + (i >> 7)]);
    }
}

// ---------------- gemm2 wrapper (bf16 A -> global_load_lds both operands) ----------------

__global__ __launch_bounds__(256) void gemm2_kernel(
    const unsigned short* __restrict__ A, const unsigned short* __restrict__ Bt,
    unsigned short* __restrict__ C)
{
    gemm_body<128, 256, false>(A, Bt, C, NV, blockIdx.x * 128, 0);
}

// ---------------- gather (bf16 in/out), 8-way edge unroll + NT stores ----------------

template<int F, bool RELU>
__global__ __launch_bounds__(256) void gather_kernel(
    const int* __restrict__ ptr, const int2* __restrict__ edat,
    const float* __restrict__ dinv, const unsigned short* __restrict__ hlin,
    const float* __restrict__ bias, unsigned short* __restrict__ hout)
{
    constexpr int V = F / 64;
    int gid = blockIdx.x * blockDim.x + threadIdx.x;
    int node = gid >> 6, lane = gid & 63;
    if (node >= NV) return;
    float dc = dinv[node];
    int j0 = ptr[node], j1 = ptr[node + 1];
    float acc[V] = {};
    const unsigned short* hb = hlin + lane * V;
    const long long* edl = (const long long*)edat;

    int j = j0;
    for (; j + 7 < j1; j += 8) {
        long long e[8];
        #pragma unroll
        for (int u = 0; u < 8; ++u) e[u] = __builtin_nontemporal_load(edl + j + u);
        if constexpr (V == 4) {
            uint2 q[8];
            #pragma unroll
            for (int u = 0; u < 8; ++u)
                q[u] = *(const uint2*)(hb + (size_t)(int)e[u] * F);
            #pragma unroll
            for (int u = 0; u < 8; ++u) {
                float n = __int_as_float((int)(e[u] >> 32));
                acc[0] += n * blo(q[u].x);
                acc[1] += n * bhi(q[u].x);
                acc[2] += n * blo(q[u].y);
                acc[3] += n * bhi(q[u].y);
            }
        } else {
            unsigned q[8];
            #pragma unroll
            for (int u = 0; u < 8; ++u)
                q[u] = *(const unsigned*)(hb + (size_t)(int)e[u] * F);
            #pragma unroll
            for (int u = 0; u < 8; ++u) {
                float n = __int_as_float((int)(e[u] >> 32));
                acc[0] += n * blo(q[u]);
                acc[1] += n * bhi(q[u]);
            }
        }
    }
    for (; j + 3 < j1; j += 4) {
        long long e[4];
        #pragma unroll
        for (int u = 0; u < 4; ++u) e[u] = __builtin_nontemporal_load(edl + j + u);
        if constexpr (V == 4) {
            uint2 q[4];
            #pragma unroll
            for (int u = 0; u < 4; ++u)
                q[u] = *(const uint2*)(hb + (size_t)(int)e[u] * F);
            #pragma unroll
            for (int u = 0; u < 4; ++u) {
                float n = __int_as_float((int)(e[u] >> 32));
                acc[0] += n * blo(q[u].x);
                acc[1] += n * bhi(q[u].x);
                acc[2] += n * blo(q[u].y);
                acc[3] += n * bhi(q[u].y);
            }
        } else {
            unsigned q[4];
            #pragma unroll
            for (int u = 0; u < 4; ++u)
                q[u] = *(const unsigned*)(hb + (size_t)(int)e[u] * F);
            #pragma unroll
            for (int u = 0; u < 4; ++u) {
                float n = __int_as_float((int)(e[u] >> 32));
                acc[0] += n * blo(q[u]);
                acc[1] += n * bhi(q[u]);
            }
        }
    }
    for (; j < j1; ++j) {
        long long e0 = __builtin_nontemporal_load(edl + j);
        float n0 = __int_as_float((int)(e0 >> 32));
        if constexpr (V == 4) {
            uint2 q0 = *(const uint2*)(hb + (size_t)(int)e0 * F);
            acc[0] += n0 * blo(q0.x);
            acc[1] += n0 * bhi(q0.x);
            acc[2] += n0 * blo(q0.y);
            acc[3] += n0 * bhi(q0.y);
        } else {
            unsigned q0 = *(const unsigned*)(hb + (size_t)(int)e0 * F);
            acc[0] += n0 * blo(q0);
            acc[1] += n0 * bhi(q0);
        }
    }

    const unsigned short* ps = hb + (size_t)node * F;
    float sw = 2.0f * dc * dc;
    if constexpr (V == 4) {
        uint2 qs = *(const uint2*)ps;
        float o0 = acc[0] + sw * blo(qs.x) + bias[lane * 4 + 0];
        float o1 = acc[1] + sw * bhi(qs.x) + bias[lane * 4 + 1];
        float o2 = acc[2] + sw * blo(qs.y) + bias[lane * 4 + 2];
        float o3 = acc[3] + sw * bhi(qs.y) + bias[lane * 4 + 3];
        if (RELU) {
            o0 = fmaxf(o0, 0.f); o1 = fmaxf(o1, 0.f);
            o2 = fmaxf(o2, 0.f); o3 = fmaxf(o3, 0.f);
        }
        union { unsigned short u[4]; unsigned long long ll; } pk;
        pk.u[0] = f2b(o0); pk.u[1] = f2b(o1); pk.u[2] = f2b(o2); pk.u[3] = f2b(o3);
        __builtin_nontemporal_store(pk.ll, (unsigned long long*)(hout + (size_t)node * F + lane * 4));
    } else {
        unsigned qs = *(const unsigned*)ps;
        float o0 = acc[0] + sw * blo(qs) + bias[lane * 2 + 0];
        float o1 = acc[1] + sw * bhi(qs) + bias[lane * 2 + 1];
        if (RELU) { o0 = fmaxf(o0, 0.f); o1 = fmaxf(o1, 0.f); }
        union { unsigned short u[2]; unsigned q; } pk;
        pk.u[0] = f2b(o0); pk.u[1] = f2b(o1);
        __builtin_nontemporal_store(pk.q, (unsigned*)(hout + (size_t)node * F + lane * 2));
    }
}

// ---------------- edge MLP via MFMA ----------------

__global__ __launch_bounds__(256) void edge_mlp_mfma_kernel(
    const int* __restrict__ pos, const int* __restrict__ neg,
    const unsigned short* __restrict__ h2, const unsigned short* __restrict__ Wl1t,
    const float* __restrict__ bl1, const float* __restrict__ Wl2,
    const float* __restrict__ bl2, float* __restrict__ out)
{
    __shared__ unsigned short Es[128][128];
    __shared__ unsigned short Ws[64][128];
    int tid = threadIdx.x;
    int lane = tid & 63, w = tid >> 6;
    int fr = lane & 15, g = lane >> 4;
    int e0 = blockIdx.x * 128;

    #pragma unroll
    for (int k = 0; k < 4; ++k) {
        int chunk = tid + k * 256;
        int row = chunk >> 4, c = chunk & 15;
        *(ushortx8*)&Ws[row][(c ^ (row & 7)) * 8] = *(const ushortx8*)&Wl1t[chunk * 8];
    }

    int et = tid >> 1, hh = tid & 1;
    int eg = e0 + et;
    int a, b;
    if (eg < EPOS) { a = pos[eg]; b = pos[EPOS + eg]; }
    else { int i = eg - EPOS; a = neg[i]; b = neg[EPOS + i]; }
    const unsigned short* pa = h2 + (size_t)a * 128 + hh * 64;
    const unsigned short* pb = h2 + (size_t)b * 128 + hh * 64;
    #pragma unroll
    for (int c8 = 0; c8 < 8; ++c8) {
        ushortx8 va = *(const ushortx8*)&pa[c8 * 8];
        ushortx8 vb = *(const ushortx8*)&pb[c8 * 8];
        ushortx8 vs = bf16add8(va, vb);
        int c = hh * 8 + c8;
        *(ushortx8*)&Es[et][(c ^ (et & 7)) * 8] = vs;
    }
    __syncthreads();

    f32x4 acc[2][4] = {};
    #pragma unroll
    for (int ks = 0; ks < 4; ++ks) {
        int c = ks * 4 + g;
        bf16x8 af[2], bfr[4];
        #pragma unroll
        for (int m = 0; m < 2; ++m) {
            int r = w * 32 + m * 16 + fr;
            af[m] = *(const bf16x8*)&Es[r][(c ^ (r & 7)) * 8];
        }
        #pragma unroll
        for (int n = 0; n < 4; ++n) {
            int r = n * 16 + fr;
            bfr[n] = *(const bf16x8*)&Ws[r][(c ^ (r & 7)) * 8];
        }
        #pragma unroll
        for (int m = 0; m < 2; ++m)
            #pragma unroll
            for (int n = 0; n < 4; ++n)
                acc[m][n] = __builtin_amdgcn_mfma_f32_16x16x32_bf16(af[m], bfr[n], acc[m][n], 0, 0, 0);
    }

    float bl2v = bl2[0];
    float b1v[4], w2v[4];
    #pragma unroll
    for (int n = 0; n < 4; ++n) {
        b1v[n] = bl1[n * 16 + fr];
        w2v[n] = Wl2[n * 16 + fr];
    }
    #pragma unroll
    for (int m = 0; m < 2; ++m) {
        float p[4];
        #pragma unroll
        for (int j = 0; j < 4; ++j) {
            float s = 0.f;
            #pragma unroll
            for (int n = 0; n < 4; ++n)
                s += fmaxf(acc[m][n][j] + b1v[n], 0.0f) * w2v[n];
            p[j] = s;
        }
        #pragma unroll
        for (int off = 1; off < 16; off <<= 1) {
            #pragma unroll
            for (int j = 0; j < 4; ++j)
                p[j] += __shfl_xor(p[j], off);
        }
        int ebase = e0 + w * 32 + m * 16 + g * 4;
        #pragma unroll
        for (int j = 0; j < 4; ++j)
            if (fr == j)
                out[ebase + j] = 1.0f / (1.0f + expf(-(p[j] + bl2v)));
    }
}

// ---------------- launch ----------------

extern "C" void kernel_launch(void* const* d_in, const int* in_sizes, int n_in,
                              void* d_out, int out_size, void* d_ws, size_t ws_size,
                              hipStream_t stream) {
    const float* x   = (const float*)d_in[0];
    const int*   tei = (const int*)d_in[1];
    const int*   pos = (const int*)d_in[2];
    const int*   neg = (const int*)d_in[3];
    const float* W1  = (const float*)d_in[4];
    const float* b1  = (const float*)d_in[5];
    const float* W2  = (const float*)d_in[6];
    const float* b2  = (const float*)d_in[7];
    const float* Wl1 = (const float*)d_in[8];
    const float* bl1 = (const float*)d_in[9];
    const float* Wl2 = (const float*)d_in[10];
    const float* bl2 = (const float*)d_in[11];
    float* out = (float*)d_out;

    // workspace (4B-word offsets)
    float* fws = (float*)d_ws;
    int*   iws = (int*)d_ws;
    unsigned short* usws = (unsigned short*)d_ws;
    float* dinv     = fws;                         // [50000]
    int*   deg      = iws + 50000;                 // [50000]
    int*   ptr      = iws + 100000;                // [50001]
    int*   cursor   = iws + 150002;                // [50000]
    int2*  edat     = (int2*)(iws + 200064);       // [800000] int2 -> ends 1800064
    unsigned short* w1t  = usws + 2ull * 1800192;  // [65536]
    unsigned short* w2t  = usws + 2ull * 1832960;  // [32768]
    unsigned short* wl1t = usws + 2ull * 1849344;  // [8192]
    unsigned short* bufX = usws + 2ull * 1853504;  // h2lin bf16
    unsigned short* bufL16 = usws + 2ull * 8253504;  // h1lin bf16, then h2 bf16
    unsigned short* bufH = usws + 2ull * 14653504;   // h1 bf16

    hipMemsetAsync(deg, 0, NV * sizeof(int), stream);

    // fat0: deg histogram + cvt(W1)
    fat0_kernel<<<3381, 256, 0, stream>>>(tei, deg, W1, w1t);

    // self-sufficient CSR scan (ptr, cursor, dinv)
    ptr2_kernel<<<49, 1024, 0, stream>>>(deg, ptr, cursor, dinv);

    // fat1: gemm1 (h1lin = bf16(x) @ w1t) + fill(edat) + cvt(W2, Wl1)
    fat1_kernel<<<4067, 256, 0, stream>>>(x, w1t, bufL16, tei, dinv, cursor, edat,
                                          W2, w2t, Wl1, wl1t);

    // layer 1 gather
    gather_kernel<256, true><<<(NV * 64) / 256, 256, 0, stream>>>(ptr, edat, dinv, bufL16, b1, bufH);

    // layer 2: h2lin = h1 @ w2t -> bufX; gather -> h2 (bufL16)
    gemm2_kernel<<<391, 256, 0, stream>>>(bufH, w2t, bufX);
    gather_kernel<128, false><<<(NV * 64) / 256, 256, 0, stream>>>(ptr, edat, dinv, bufX, b2, bufL16);

    // edge MLP head (MFMA)
    edge_mlp_mfma_kernel<<<ETEST / 128, 256, 0, stream>>>(pos, neg, bufL16, wl1t, bl1, Wl2, bl2, out);
}

// Round 15
// 262.807 us; speedup vs baseline: 2.7177x; 1.0703x over previous
//
#include <hip/hip_runtime.h>
#include <math.h>

#define NV 50000
#define ETR 800000
#define EPOS 200000
#define ETEST 400000

typedef __attribute__((ext_vector_type(8))) short bf16x8;
typedef __attribute__((ext_vector_type(8))) unsigned short ushortx8;
typedef __attribute__((ext_vector_type(4))) float f32x4;

__device__ inline unsigned short f2b(float f) {
    union { float f; unsigned u; } v; v.f = f;
    unsigned r = v.u + 0x7fffu + ((v.u >> 16) & 1u);   // RNE
    return (unsigned short)(r >> 16);
}
__device__ inline float blo(unsigned q) { union { unsigned u; float f; } v; v.u = q << 16; return v.f; }
__device__ inline float bhi(unsigned q) { union { unsigned u; float f; } v; v.u = q & 0xffff0000u; return v.f; }
__device__ inline float b2f(unsigned short s) { union { unsigned u; float f; } v; v.u = ((unsigned)s) << 16; return v.f; }

// direct-to-LDS 16B load (linear LDS dest; swizzle applied on the GLOBAL side)
#define GLOAD_LDS16(g, l) __builtin_amdgcn_global_load_lds( \
    (__attribute__((address_space(1))) void*)(g), \
    (__attribute__((address_space(3))) void*)(l), 16, 0, 0)

// ---------------- shared GEMM body (128x128 tile, 4 waves 2x2, BK=64) ----------------
// NCOLS masks the C store width (for N<128 outputs from the 128-wide tile).

template<int N, int K, bool AF32, int NCOLS = N>
__device__ __forceinline__ void gemm_body(
    const void* __restrict__ Av, const unsigned short* __restrict__ Bt,
    unsigned short* __restrict__ C, int M, int row0, int col0)
{
    constexpr int BK = 64;
    __shared__ unsigned short smem[18464];   // staging 32KB, then C-stage 4 x 4616
    unsigned short (*Asm)[BK] = (unsigned short (*)[BK])smem;          // [128][64]
    unsigned short (*Bsm)[BK] = (unsigned short (*)[BK])(smem + 8192); // [128][64]
    int tid = threadIdx.x;
    int lane = tid & 63, wid = tid >> 6;
    int wr = wid >> 1, wc = wid & 1;

    int sr = tid >> 3;                 // 0..31
    int s8 = tid & 7;                  // linear 16B slot (LDS dest)
    int fr = lane & 15;
    int g  = lane >> 4;

    f32x4 acc[4][4] = {};

    for (int k0 = 0; k0 < K; k0 += BK) {
        #pragma unroll
        for (int i = 0; i < 4; ++i) {
            int r = sr + i * 32;
            int gr = row0 + r;
            int s8sw = s8 ^ (r & 7);   // pre-swizzled global chunk (involution)
            GLOAD_LDS16(&Bt[(size_t)(col0 + r) * K + k0 + s8sw * 8], &Bsm[r][s8 * 8]);
            if constexpr (AF32) {
                const float* Af = (const float*)Av;
                ushortx8 va = {0, 0, 0, 0, 0, 0, 0, 0};
                if (gr < M) {
                    float4 f0 = *(const float4*)&Af[(size_t)gr * K + k0 + s8 * 8];
                    float4 f1 = *(const float4*)&Af[(size_t)gr * K + k0 + s8 * 8 + 4];
                    va[0] = f2b(f0.x); va[1] = f2b(f0.y); va[2] = f2b(f0.z); va[3] = f2b(f0.w);
                    va[4] = f2b(f1.x); va[5] = f2b(f1.y); va[6] = f2b(f1.z); va[7] = f2b(f1.w);
                }
                *(ushortx8*)&Asm[r][(s8 ^ (r & 7)) * 8] = va;   // swizzled write (same content)
            } else {
                const unsigned short* Ab = (const unsigned short*)Av;
                GLOAD_LDS16(&Ab[(size_t)gr * K + k0 + s8sw * 8], &Asm[r][s8 * 8]);
            }
        }
        __syncthreads();
        #pragma unroll
        for (int kf = 0; kf < BK; kf += 32) {
            int sbase = kf >> 3;
            bf16x8 af[4], bfr[4];
            #pragma unroll
            for (int m = 0; m < 4; ++m) {
                int rr = wr * 64 + m * 16 + fr;
                af[m] = *(const bf16x8*)&Asm[rr][((sbase + g) ^ (fr & 7)) * 8];
            }
            #pragma unroll
            for (int n = 0; n < 4; ++n) {
                int rr = wc * 64 + n * 16 + fr;
                bfr[n] = *(const bf16x8*)&Bsm[rr][((sbase + g) ^ (fr & 7)) * 8];
            }
            #pragma unroll
            for (int m = 0; m < 4; ++m)
                #pragma unroll
                for (int n = 0; n < 4; ++n)
                    acc[m][n] = __builtin_amdgcn_mfma_f32_16x16x32_bf16(af[m], bfr[n], acc[m][n], 0, 0, 0);
        }
        __syncthreads();
    }

    // ---- epilogue: C/D layout col=lane&15, row=(lane>>4)*4+j ; LDS-staged store ----
    {
        unsigned short* cw = smem + wid * 4616;   // per-wave [64][72] + skew
        #pragma unroll
        for (int m = 0; m < 4; ++m)
            #pragma unroll
            for (int n = 0; n < 4; ++n)
                #pragma unroll
                for (int j = 0; j < 4; ++j)
                    cw[(m * 16 + g * 4 + j) * 72 + n * 16 + fr] = f2b(acc[m][n][j]);
        __syncthreads();
        int row = tid >> 1;                   // 0..127
        int half = tid & 1;                   // col quadrant
        int q = ((row >> 6) << 1) + half;     // owning wave quadrant
        int rl = row & 63;
        const unsigned short* cr = smem + q * 4616 + rl * 72;
        int gr = row0 + row;
        if (gr < M && half * 64 < NCOLS) {
            unsigned short* gp = C + (size_t)gr * NCOLS + col0 + half * 64;
            #pragma unroll
            for (int c8 = 0; c8 < 8; ++c8)
                *(ushortx8*)&gp[c8 * 8] = *(const ushortx8*)&cr[c8 * 8];
        }
    }
}

// ---------------- fat0: deg histogram (blocks 0..3124) + cvt W1 (3125..3380) ----------------

__global__ __launch_bounds__(256) void fat0_kernel(
    const int* __restrict__ tei, int* __restrict__ deg,
    const float* __restrict__ W1, unsigned short* __restrict__ w1t)
{
    int bid = blockIdx.x;
    int t = threadIdx.x;
    if (bid < 3125) {
        int e = bid * 256 + t;
        if (e < ETR) atomicAdd(&deg[tei[ETR + e]], 1);
    } else {
        int i = (bid - 3125) * 256 + t;        // 0..65535
        w1t[i] = f2b(W1[(i & 255) * 256 + (i >> 8)]);
    }
}

// ---------------- ptr2: self-sufficient scan (49 blocks x 1024) ----------------

__global__ __launch_bounds__(1024) void ptr2_kernel(
    const int* __restrict__ deg, int* __restrict__ ptr,
    int* __restrict__ cursor, float* __restrict__ dinv)
{
    int b = blockIdx.x, t = threadIdx.x;
    int lane = t & 63, w = t >> 6;
    __shared__ int wred[16], wsum[16], woff[16];
    __shared__ int base_s;

    int pre = 0;
    int lim = b * 1024;
    for (int i = t; i < lim; i += 1024) pre += deg[i];
    #pragma unroll
    for (int off = 32; off > 0; off >>= 1) pre += __shfl_xor(pre, off);
    if (lane == 0) wred[w] = pre;
    __syncthreads();
    if (t == 0) {
        int s = 0;
        #pragma unroll
        for (int k = 0; k < 16; ++k) s += wred[k];
        base_s = s;
    }

    int i = b * 1024 + t;
    int d = (i < NV) ? deg[i] : 0;
    int v = d;
    #pragma unroll
    for (int off = 1; off < 64; off <<= 1) {
        int u = __shfl_up(v, off);
        if (lane >= off) v += u;
    }
    if (lane == 63) wsum[w] = v;
    __syncthreads();
    if (t == 0) {
        int s = base_s;
        #pragma unroll
        for (int k = 0; k < 16; ++k) { woff[k] = s; s += wsum[k]; }
    }
    __syncthreads();
    int excl = woff[w] + v - d;
    if (i < NV) {
        ptr[i] = excl;
        cursor[i] = excl;
        dinv[i] = rsqrtf((float)d + 2.0f);   // SELF_LOOP_W = 2
        if (i == NV - 1) ptr[NV] = excl + d;
    }
}

// ---------------- fat1: gemm1 (0..781) + fill (782..3906) + cvt W2 (3907..4034)
//                       + cvt Wl1 (4035..4066) + zero-pad wl1t rows 64..127 (4067..4098) ----------------

__global__ __launch_bounds__(256) void fat1_kernel(
    const float* __restrict__ x, const unsigned short* __restrict__ w1t,
    unsigned short* __restrict__ h1lin,
    const int* __restrict__ tei, const float* __restrict__ dinv,
    int* __restrict__ cursor, int2* __restrict__ edat,
    const float* __restrict__ W2, unsigned short* __restrict__ w2t,
    const float* __restrict__ Wl1, unsigned short* __restrict__ wl1t)
{
    int bid = blockIdx.x;
    int t = threadIdx.x;
    if (bid < 782) {
        int row0 = (bid >> 1) * 128, col0 = (bid & 1) * 128;
        gemm_body<256, 256, true>(x, w1t, h1lin, NV, row0, col0);
    } else if (bid < 3907) {
        int e = (bid - 782) * 256 + t;
        if (e < ETR) {
            int row = tei[e];
            int col = tei[ETR + e];
            int p = atomicAdd(&cursor[col], 1);
            edat[p] = make_int2(row, __float_as_int(dinv[row] * dinv[col]));
        }
    } else if (bid < 4035) {
        int i = (bid - 3907) * 256 + t;        // 0..32767
        w2t[i] = f2b(W2[(i & 255) * 128 + (i >> 8)]);
    } else if (bid < 4067) {
        int i = (bid - 4035) * 256 + t;        // 0..8191  (rows 0..63)
        wl1t[i] = f2b(Wl1[(i & 127) * 64 + (i >> 7)]);
    } else {
        int i = (bid - 4067) * 256 + t;        // 0..8191  (rows 64..127 = zero pad)
        wl1t[8192 + i] = 0;
    }
}

// ---------------- gemm wrappers ----------------

__global__ __launch_bounds__(256) void gemm2_kernel(
    const unsigned short* __restrict__ A, const unsigned short* __restrict__ Bt,
    unsigned short* __restrict__ C)
{
    gemm_body<128, 256, false>(A, Bt, C, NV, blockIdx.x * 128, 0);
}

// u[node][64] = h2[node][128] @ Wl1 (Wl1t padded to 128 rows; only 64 cols stored)
__global__ __launch_bounds__(256) void gemm_u_kernel(
    const unsigned short* __restrict__ A, const unsigned short* __restrict__ Bt,
    unsigned short* __restrict__ C)
{
    gemm_body<128, 128, false, 64>(A, Bt, C, NV, blockIdx.x * 128, 0);
}

// ---------------- gather (bf16 in/out), 8-way edge unroll + NT stores ----------------

template<int F, bool RELU>
__global__ __launch_bounds__(256) void gather_kernel(
    const int* __restrict__ ptr, const int2* __restrict__ edat,
    const float* __restrict__ dinv, const unsigned short* __restrict__ hlin,
    const float* __restrict__ bias, unsigned short* __restrict__ hout)
{
    constexpr int V = F / 64;
    int gid = blockIdx.x * blockDim.x + threadIdx.x;
    int node = gid >> 6, lane = gid & 63;
    if (node >= NV) return;
    float dc = dinv[node];
    int j0 = ptr[node], j1 = ptr[node + 1];
    float acc[V] = {};
    const unsigned short* hb = hlin + lane * V;
    const long long* edl = (const long long*)edat;

    int j = j0;
    for (; j + 7 < j1; j += 8) {
        long long e[8];
        #pragma unroll
        for (int u = 0; u < 8; ++u) e[u] = __builtin_nontemporal_load(edl + j + u);
        if constexpr (V == 4) {
            uint2 q[8];
            #pragma unroll
            for (int u = 0; u < 8; ++u)
                q[u] = *(const uint2*)(hb + (size_t)(int)e[u] * F);
            #pragma unroll
            for (int u = 0; u < 8; ++u) {
                float n = __int_as_float((int)(e[u] >> 32));
                acc[0] += n * blo(q[u].x);
                acc[1] += n * bhi(q[u].x);
                acc[2] += n * blo(q[u].y);
                acc[3] += n * bhi(q[u].y);
            }
        } else {
            unsigned q[8];
            #pragma unroll
            for (int u = 0; u < 8; ++u)
                q[u] = *(const unsigned*)(hb + (size_t)(int)e[u] * F);
            #pragma unroll
            for (int u = 0; u < 8; ++u) {
                float n = __int_as_float((int)(e[u] >> 32));
                acc[0] += n * blo(q[u]);
                acc[1] += n * bhi(q[u]);
            }
        }
    }
    for (; j + 3 < j1; j += 4) {
        long long e[4];
        #pragma unroll
        for (int u = 0; u < 4; ++u) e[u] = __builtin_nontemporal_load(edl + j + u);
        if constexpr (V == 4) {
            uint2 q[4];
            #pragma unroll
            for (int u = 0; u < 4; ++u)
                q[u] = *(const uint2*)(hb + (size_t)(int)e[u] * F);
            #pragma unroll
            for (int u = 0; u < 4; ++u) {
                float n = __int_as_float((int)(e[u] >> 32));
                acc[0] += n * blo(q[u].x);
                acc[1] += n * bhi(q[u].x);
                acc[2] += n * blo(q[u].y);
                acc[3] += n * bhi(q[u].y);
            }
        } else {
            unsigned q[4];
            #pragma unroll
            for (int u = 0; u < 4; ++u)
                q[u] = *(const unsigned*)(hb + (size_t)(int)e[u] * F);
            #pragma unroll
            for (int u = 0; u < 4; ++u) {
                float n = __int_as_float((int)(e[u] >> 32));
                acc[0] += n * blo(q[u]);
                acc[1] += n * bhi(q[u]);
            }
        }
    }
    for (; j < j1; ++j) {
        long long e0 = __builtin_nontemporal_load(edl + j);
        float n0 = __int_as_float((int)(e0 >> 32));
        if constexpr (V == 4) {
            uint2 q0 = *(const uint2*)(hb + (size_t)(int)e0 * F);
            acc[0] += n0 * blo(q0.x);
            acc[1] += n0 * bhi(q0.x);
            acc[2] += n0 * blo(q0.y);
            acc[3] += n0 * bhi(q0.y);
        } else {
            unsigned q0 = *(const unsigned*)(hb + (size_t)(int)e0 * F);
            acc[0] += n0 * blo(q0);
            acc[1] += n0 * bhi(q0);
        }
    }

    const unsigned short* ps = hb + (size_t)node * F;
    float sw = 2.0f * dc * dc;
    if constexpr (V == 4) {
        uint2 qs = *(const uint2*)ps;
        float o0 = acc[0] + sw * blo(qs.x) + bias[lane * 4 + 0];
        float o1 = acc[1] + sw * bhi(qs.x) + bias[lane * 4 + 1];
        float o2 = acc[2] + sw * blo(qs.y) + bias[lane * 4 + 2];
        float o3 = acc[3] + sw * bhi(qs.y) + bias[lane * 4 + 3];
        if (RELU) {
            o0 = fmaxf(o0, 0.f); o1 = fmaxf(o1, 0.f);
            o2 = fmaxf(o2, 0.f); o3 = fmaxf(o3, 0.f);
        }
        union { unsigned short u[4]; unsigned long long ll; } pk;
        pk.u[0] = f2b(o0); pk.u[1] = f2b(o1); pk.u[2] = f2b(o2); pk.u[3] = f2b(o3);
        __builtin_nontemporal_store(pk.ll, (unsigned long long*)(hout + (size_t)node * F + lane * 4));
    } else {
        unsigned qs = *(const unsigned*)ps;
        float o0 = acc[0] + sw * blo(qs) + bias[lane * 2 + 0];
        float o1 = acc[1] + sw * bhi(qs) + bias[lane * 2 + 1];
        if (RELU) { o0 = fmaxf(o0, 0.f); o1 = fmaxf(o1, 0.f); }
        union { unsigned short u[2]; unsigned q; } pk;
        pk.u[0] = f2b(o0); pk.u[1] = f2b(o1);
        __builtin_nontemporal_store(pk.q, (unsigned*)(hout + (size_t)node * F + lane * 2));
    }
}

// ---------------- edge head: out[e] = sigmoid(relu(u[a]+u[b]+bl1) . Wl2 + bl2) ----------------
// 16 lanes per edge, 4 bf16 per lane (128B row reads from the 6.4MB u table).

__global__ __launch_bounds__(256) void edge_head_kernel(
    const int* __restrict__ pos, const int* __restrict__ neg,
    const unsigned short* __restrict__ u,
    const float* __restrict__ bl1, const float* __restrict__ Wl2,
    const float* __restrict__ bl2, float* __restrict__ out)
{
    int tid = threadIdx.x;
    int wv = tid >> 6, lane = tid & 63;
    int sub = lane >> 4, fl = lane & 15;
    int e = blockIdx.x * 16 + wv * 4 + sub;
    if (e >= ETEST) return;
    int a, b;
    if (e < EPOS) { a = pos[e]; b = pos[EPOS + e]; }
    else { int i = e - EPOS; a = neg[i]; b = neg[EPOS + i]; }
    uint2 qa = *(const uint2*)&u[(size_t)a * 64 + fl * 4];
    uint2 qb = *(const uint2*)&u[(size_t)b * 64 + fl * 4];
    float4 b1 = *(const float4*)&bl1[fl * 4];
    float4 w2 = *(const float4*)&Wl2[fl * 4];
    float s = fmaxf(blo(qa.x) + blo(qb.x) + b1.x, 0.f) * w2.x
            + fmaxf(bhi(qa.x) + bhi(qb.x) + b1.y, 0.f) * w2.y
            + fmaxf(blo(qa.y) + blo(qb.y) + b1.z, 0.f) * w2.z
            + fmaxf(bhi(qa.y) + bhi(qb.y) + b1.w, 0.f) * w2.w;
    #pragma unroll
    for (int off = 8; off > 0; off >>= 1)
        s += __shfl_xor(s, off);     // stays within the 16-lane group
    if (fl == 0)
        out[e] = 1.0f / (1.0f + expf(-(s + bl2[0])));
}

// ---------------- launch ----------------

extern "C" void kernel_launch(void* const* d_in, const int* in_sizes, int n_in,
                              void* d_out, int out_size, void* d_ws, size_t ws_size,
                              hipStream_t stream) {
    const float* x   = (const float*)d_in[0];
    const int*   tei = (const int*)d_in[1];
    const int*   pos = (const int*)d_in[2];
    const int*   neg = (const int*)d_in[3];
    const float* W1  = (const float*)d_in[4];
    const float* b1  = (const float*)d_in[5];
    const float* W2  = (const float*)d_in[6];
    const float* b2  = (const float*)d_in[7];
    const float* Wl1 = (const float*)d_in[8];
    const float* bl1 = (const float*)d_in[9];
    const float* Wl2 = (const float*)d_in[10];
    const float* bl2 = (const float*)d_in[11];
    float* out = (float*)d_out;

    // workspace (4B-word offsets, ~90.6MB total)
    float* fws = (float*)d_ws;
    int*   iws = (int*)d_ws;
    unsigned short* usws = (unsigned short*)d_ws;
    float* dinv     = fws;                         // [50000]
    int*   deg      = iws + 50000;                 // [50000]
    int*   ptr      = iws + 100000;                // [50001]
    int*   cursor   = iws + 150002;                // [50000]
    int2*  edat     = (int2*)(iws + 200064);       // [800000] int2 -> ends 1800064
    unsigned short* w1t  = usws + 2ull * 1800192;  // [65536]
    unsigned short* w2t  = usws + 2ull * 1832960;  // [32768]
    unsigned short* bufX = usws + 2ull * 1853504;  // h2lin bf16
    unsigned short* bufL16 = usws + 2ull * 8253504;  // h1lin bf16, then h2 bf16
    unsigned short* bufH = usws + 2ull * 14653504;   // h1 bf16 -> ends w 21053504
    unsigned short* wl1t = usws + 2ull * 21053504; // [128*128] padded -> w 21061696
    unsigned short* ubuf = usws + 2ull * 21061696; // u [50000*64] -> w 22661696 (90.6MB)

    hipMemsetAsync(deg, 0, NV * sizeof(int), stream);

    // fat0: deg histogram + cvt(W1)
    fat0_kernel<<<3381, 256, 0, stream>>>(tei, deg, W1, w1t);

    // self-sufficient CSR scan (ptr, cursor, dinv)
    ptr2_kernel<<<49, 1024, 0, stream>>>(deg, ptr, cursor, dinv);

    // fat1: gemm1 + fill(edat) + cvt(W2, Wl1 + zero-pad)
    fat1_kernel<<<4099, 256, 0, stream>>>(x, w1t, bufL16, tei, dinv, cursor, edat,
                                          W2, w2t, Wl1, wl1t);

    // layer 1 gather
    gather_kernel<256, true><<<(NV * 64) / 256, 256, 0, stream>>>(ptr, edat, dinv, bufL16, b1, bufH);

    // layer 2: h2lin = h1 @ w2t -> bufX; gather -> h2 (bufL16)
    gemm2_kernel<<<391, 256, 0, stream>>>(bufH, w2t, bufX);
    gather_kernel<128, false><<<(NV * 64) / 256, 256, 0, stream>>>(ptr, edat, dinv, bufX, b2, bufL16);

    // edge head: u = h2 @ Wl1 (per node), then per-edge MLP on u
    gemm_u_kernel<<<391, 256, 0, stream>>>(bufL16, wl1t, ubuf);
    edge_head_kernel<<<ETEST / 16, 256, 0, stream>>>(pos, neg, ubuf, bl1, Wl2, bl2, out);
}

// Round 16
// 254.585 us; speedup vs baseline: 2.8055x; 1.0323x over previous
//
#include <hip/hip_runtime.h>
#include <math.h>

#define NV 50000
#define ETR 800000
#define EPOS 200000
#define ETEST 400000

typedef __attribute__((ext_vector_type(8))) short bf16x8;
typedef __attribute__((ext_vector_type(8))) unsigned short ushortx8;
typedef __attribute__((ext_vector_type(4))) float f32x4;

__device__ inline unsigned short f2b(float f) {
    union { float f; unsigned u; } v; v.f = f;
    unsigned r = v.u + 0x7fffu + ((v.u >> 16) & 1u);   // RNE
    return (unsigned short)(r >> 16);
}
__device__ inline float blo(unsigned q) { union { unsigned u; float f; } v; v.u = q << 16; return v.f; }
__device__ inline float bhi(unsigned q) { union { unsigned u; float f; } v; v.u = q & 0xffff0000u; return v.f; }
__device__ inline float b2f(unsigned short s) { union { unsigned u; float f; } v; v.u = ((unsigned)s) << 16; return v.f; }

// direct-to-LDS 16B load (linear LDS dest; swizzle applied on the GLOBAL side)
#define GLOAD_LDS16(g, l) __builtin_amdgcn_global_load_lds( \
    (__attribute__((address_space(1))) void*)(g), \
    (__attribute__((address_space(3))) void*)(l), 16, 0, 0)

// ---------------- shared GEMM body (128x128 tile, 4 waves 2x2, BK=64) ----------------
// NCOLS masks the C store width (for N<128 outputs from the 128-wide tile).

template<int N, int K, bool AF32, int NCOLS = N>
__device__ __forceinline__ void gemm_body(
    const void* __restrict__ Av, const unsigned short* __restrict__ Bt,
    unsigned short* __restrict__ C, int M, int row0, int col0)
{
    constexpr int BK = 64;
    __shared__ unsigned short smem[18464];   // staging 32KB, then C-stage 4 x 4616
    unsigned short (*Asm)[BK] = (unsigned short (*)[BK])smem;          // [128][64]
    unsigned short (*Bsm)[BK] = (unsigned short (*)[BK])(smem + 8192); // [128][64]
    int tid = threadIdx.x;
    int lane = tid & 63, wid = tid >> 6;
    int wr = wid >> 1, wc = wid & 1;

    int sr = tid >> 3;                 // 0..31
    int s8 = tid & 7;                  // linear 16B slot (LDS dest)
    int fr = lane & 15;
    int g  = lane >> 4;

    f32x4 acc[4][4] = {};

    for (int k0 = 0; k0 < K; k0 += BK) {
        #pragma unroll
        for (int i = 0; i < 4; ++i) {
            int r = sr + i * 32;
            int gr = row0 + r;
            int s8sw = s8 ^ (r & 7);   // pre-swizzled global chunk (involution)
            GLOAD_LDS16(&Bt[(size_t)(col0 + r) * K + k0 + s8sw * 8], &Bsm[r][s8 * 8]);
            if constexpr (AF32) {
                const float* Af = (const float*)Av;
                ushortx8 va = {0, 0, 0, 0, 0, 0, 0, 0};
                if (gr < M) {
                    float4 f0 = *(const float4*)&Af[(size_t)gr * K + k0 + s8 * 8];
                    float4 f1 = *(const float4*)&Af[(size_t)gr * K + k0 + s8 * 8 + 4];
                    va[0] = f2b(f0.x); va[1] = f2b(f0.y); va[2] = f2b(f0.z); va[3] = f2b(f0.w);
                    va[4] = f2b(f1.x); va[5] = f2b(f1.y); va[6] = f2b(f1.z); va[7] = f2b(f1.w);
                }
                *(ushortx8*)&Asm[r][(s8 ^ (r & 7)) * 8] = va;   // swizzled write (same content)
            } else {
                const unsigned short* Ab = (const unsigned short*)Av;
                GLOAD_LDS16(&Ab[(size_t)gr * K + k0 + s8sw * 8], &Asm[r][s8 * 8]);
            }
        }
        __syncthreads();
        #pragma unroll
        for (int kf = 0; kf < BK; kf += 32) {
            int sbase = kf >> 3;
            bf16x8 af[4], bfr[4];
            #pragma unroll
            for (int m = 0; m < 4; ++m) {
                int rr = wr * 64 + m * 16 + fr;
                af[m] = *(const bf16x8*)&Asm[rr][((sbase + g) ^ (fr & 7)) * 8];
            }
            #pragma unroll
            for (int n = 0; n < 4; ++n) {
                int rr = wc * 64 + n * 16 + fr;
                bfr[n] = *(const bf16x8*)&Bsm[rr][((sbase + g) ^ (fr & 7)) * 8];
            }
            #pragma unroll
            for (int m = 0; m < 4; ++m)
                #pragma unroll
                for (int n = 0; n < 4; ++n)
                    acc[m][n] = __builtin_amdgcn_mfma_f32_16x16x32_bf16(af[m], bfr[n], acc[m][n], 0, 0, 0);
        }
        __syncthreads();
    }

    // ---- epilogue: C/D layout col=lane&15, row=(lane>>4)*4+j ; LDS-staged store ----
    {
        unsigned short* cw = smem + wid * 4616;   // per-wave [64][72] + skew
        #pragma unroll
        for (int m = 0; m < 4; ++m)
            #pragma unroll
            for (int n = 0; n < 4; ++n)
                #pragma unroll
                for (int j = 0; j < 4; ++j)
                    cw[(m * 16 + g * 4 + j) * 72 + n * 16 + fr] = f2b(acc[m][n][j]);
        __syncthreads();
        int row = tid >> 1;                   // 0..127
        int half = tid & 1;                   // col quadrant
        int q = ((row >> 6) << 1) + half;     // owning wave quadrant
        int rl = row & 63;
        const unsigned short* cr = smem + q * 4616 + rl * 72;
        int gr = row0 + row;
        if (gr < M && half * 64 < NCOLS) {
            unsigned short* gp = C + (size_t)gr * NCOLS + col0 + half * 64;
            #pragma unroll
            for (int c8 = 0; c8 < 8; ++c8)
                *(ushortx8*)&gp[c8 * 8] = *(const ushortx8*)&cr[c8 * 8];
        }
    }
}

// ---------------- fat0: deg hist (0..3124) + cvt W1 (3125..3380)
//                       + Wc = W2@Wl1 bf16^T padded (3381..3508) + c2 = b2@Wl1 (3509) ----------------

__global__ __launch_bounds__(256) void fat0_kernel(
    const int* __restrict__ tei, int* __restrict__ deg,
    const float* __restrict__ W1, unsigned short* __restrict__ w1t,
    const float* __restrict__ W2, const float* __restrict__ Wl1,
    const float* __restrict__ b2, unsigned short* __restrict__ wct,
    float* __restrict__ c2f)
{
    int bid = blockIdx.x;
    int t = threadIdx.x;
    if (bid < 3125) {
        int e = bid * 256 + t;
        if (e < ETR) atomicAdd(&deg[tei[ETR + e]], 1);
    } else if (bid < 3381) {
        int i = (bid - 3125) * 256 + t;        // 0..65535
        w1t[i] = f2b(W1[(i & 255) * 256 + (i >> 8)]);
    } else if (bid < 3509) {
        // wct[n][k] = bf16( sum_j W2[k][j] * Wl1[j][n] ), n<64; zero-pad n in 64..127
        int n = bid - 3381;                    // 0..127
        int k = t;                             // 0..255
        if (n < 64) {
            float s = 0.f;
            for (int j = 0; j < 128; ++j)
                s += W2[k * 128 + j] * Wl1[j * 64 + n];
            wct[n * 256 + k] = f2b(s);
        } else {
            wct[n * 256 + k] = 0;
        }
    } else {
        if (t < 64) {
            float s = 0.f;
            for (int j = 0; j < 128; ++j)
                s += b2[j] * Wl1[j * 64 + t];
            c2f[t] = s;
        }
    }
}

// ---------------- ptr2: self-sufficient scan (49 blocks x 1024) ----------------

__global__ __launch_bounds__(1024) void ptr2_kernel(
    const int* __restrict__ deg, int* __restrict__ ptr,
    int* __restrict__ cursor, float* __restrict__ dinv)
{
    int b = blockIdx.x, t = threadIdx.x;
    int lane = t & 63, w = t >> 6;
    __shared__ int wred[16], wsum[16], woff[16];
    __shared__ int base_s;

    int pre = 0;
    int lim = b * 1024;
    for (int i = t; i < lim; i += 1024) pre += deg[i];
    #pragma unroll
    for (int off = 32; off > 0; off >>= 1) pre += __shfl_xor(pre, off);
    if (lane == 0) wred[w] = pre;
    __syncthreads();
    if (t == 0) {
        int s = 0;
        #pragma unroll
        for (int k = 0; k < 16; ++k) s += wred[k];
        base_s = s;
    }

    int i = b * 1024 + t;
    int d = (i < NV) ? deg[i] : 0;
    int v = d;
    #pragma unroll
    for (int off = 1; off < 64; off <<= 1) {
        int u = __shfl_up(v, off);
        if (lane >= off) v += u;
    }
    if (lane == 63) wsum[w] = v;
    __syncthreads();
    if (t == 0) {
        int s = base_s;
        #pragma unroll
        for (int k = 0; k < 16; ++k) { woff[k] = s; s += wsum[k]; }
    }
    __syncthreads();
    int excl = woff[w] + v - d;
    if (i < NV) {
        ptr[i] = excl;
        cursor[i] = excl;
        dinv[i] = rsqrtf((float)d + 2.0f);   // SELF_LOOP_W = 2
        if (i == NV - 1) ptr[NV] = excl + d;
    }
}

// ---------------- fat1: gemm1 (0..781) + fill (782..3906) ----------------

__global__ __launch_bounds__(256) void fat1_kernel(
    const float* __restrict__ x, const unsigned short* __restrict__ w1t,
    unsigned short* __restrict__ h1lin,
    const int* __restrict__ tei, const float* __restrict__ dinv,
    int* __restrict__ cursor, int2* __restrict__ edat)
{
    int bid = blockIdx.x;
    int t = threadIdx.x;
    if (bid < 782) {
        int row0 = (bid >> 1) * 128, col0 = (bid & 1) * 128;
        gemm_body<256, 256, true>(x, w1t, h1lin, NV, row0, col0);
    } else {
        int e = (bid - 782) * 256 + t;
        if (e < ETR) {
            int row = tei[e];
            int col = tei[ETR + e];
            int p = atomicAdd(&cursor[col], 1);
            edat[p] = make_int2(row, __float_as_int(dinv[row] * dinv[col]));
        }
    }
}

// ---------------- gemm_v: v[50k][64] = h1[50k][256] @ Wc (wct padded to 128 rows) ----------------

__global__ __launch_bounds__(256) void gemm_v_kernel(
    const unsigned short* __restrict__ A, const unsigned short* __restrict__ Bt,
    unsigned short* __restrict__ C)
{
    gemm_body<128, 256, false, 64>(A, Bt, C, NV, blockIdx.x * 128, 0);
}

// ---------------- gather (bf16 in/out), 8-way edge unroll + NT stores ----------------
// V = F/64 bf16 per lane (V=4: F=256, V=1: F=64).

template<int F, bool RELU>
__global__ __launch_bounds__(256) void gather_kernel(
    const int* __restrict__ ptr, const int2* __restrict__ edat,
    const float* __restrict__ dinv, const unsigned short* __restrict__ hlin,
    const float* __restrict__ bias, unsigned short* __restrict__ hout)
{
    constexpr int V = F / 64;
    int gid = blockIdx.x * blockDim.x + threadIdx.x;
    int node = gid >> 6, lane = gid & 63;
    if (node >= NV) return;
    float dc = dinv[node];
    int j0 = ptr[node], j1 = ptr[node + 1];
    float acc[V] = {};
    const unsigned short* hb = hlin + lane * V;
    const long long* edl = (const long long*)edat;

    int j = j0;
    for (; j + 7 < j1; j += 8) {
        long long e[8];
        #pragma unroll
        for (int u = 0; u < 8; ++u) e[u] = __builtin_nontemporal_load(edl + j + u);
        if constexpr (V == 4) {
            uint2 q[8];
            #pragma unroll
            for (int u = 0; u < 8; ++u)
                q[u] = *(const uint2*)(hb + (size_t)(int)e[u] * F);
            #pragma unroll
            for (int u = 0; u < 8; ++u) {
                float n = __int_as_float((int)(e[u] >> 32));
                acc[0] += n * blo(q[u].x);
                acc[1] += n * bhi(q[u].x);
                acc[2] += n * blo(q[u].y);
                acc[3] += n * bhi(q[u].y);
            }
        } else {
            unsigned short q[8];
            #pragma unroll
            for (int u = 0; u < 8; ++u)
                q[u] = hb[(size_t)(int)e[u] * F];
            #pragma unroll
            for (int u = 0; u < 8; ++u) {
                float n = __int_as_float((int)(e[u] >> 32));
                acc[0] += n * b2f(q[u]);
            }
        }
    }
    for (; j + 3 < j1; j += 4) {
        long long e[4];
        #pragma unroll
        for (int u = 0; u < 4; ++u) e[u] = __builtin_nontemporal_load(edl + j + u);
        if constexpr (V == 4) {
            uint2 q[4];
            #pragma unroll
            for (int u = 0; u < 4; ++u)
                q[u] = *(const uint2*)(hb + (size_t)(int)e[u] * F);
            #pragma unroll
            for (int u = 0; u < 4; ++u) {
                float n = __int_as_float((int)(e[u] >> 32));
                acc[0] += n * blo(q[u].x);
                acc[1] += n * bhi(q[u].x);
                acc[2] += n * blo(q[u].y);
                acc[3] += n * bhi(q[u].y);
            }
        } else {
            unsigned short q[4];
            #pragma unroll
            for (int u = 0; u < 4; ++u)
                q[u] = hb[(size_t)(int)e[u] * F];
            #pragma unroll
            for (int u = 0; u < 4; ++u) {
                float n = __int_as_float((int)(e[u] >> 32));
                acc[0] += n * b2f(q[u]);
            }
        }
    }
    for (; j < j1; ++j) {
        long long e0 = __builtin_nontemporal_load(edl + j);
        float n0 = __int_as_float((int)(e0 >> 32));
        if constexpr (V == 4) {
            uint2 q0 = *(const uint2*)(hb + (size_t)(int)e0 * F);
            acc[0] += n0 * blo(q0.x);
            acc[1] += n0 * bhi(q0.x);
            acc[2] += n0 * blo(q0.y);
            acc[3] += n0 * bhi(q0.y);
        } else {
            acc[0] += n0 * b2f(hb[(size_t)(int)e0 * F]);
        }
    }

    const unsigned short* ps = hb + (size_t)node * F;
    float sw = 2.0f * dc * dc;
    if constexpr (V == 4) {
        uint2 qs = *(const uint2*)ps;
        float o0 = acc[0] + sw * blo(qs.x) + bias[lane * 4 + 0];
        float o1 = acc[1] + sw * bhi(qs.x) + bias[lane * 4 + 1];
        float o2 = acc[2] + sw * blo(qs.y) + bias[lane * 4 + 2];
        float o3 = acc[3] + sw * bhi(qs.y) + bias[lane * 4 + 3];
        if (RELU) {
            o0 = fmaxf(o0, 0.f); o1 = fmaxf(o1, 0.f);
            o2 = fmaxf(o2, 0.f); o3 = fmaxf(o3, 0.f);
        }
        union { unsigned short u[4]; unsigned long long ll; } pk;
        pk.u[0] = f2b(o0); pk.u[1] = f2b(o1); pk.u[2] = f2b(o2); pk.u[3] = f2b(o3);
        __builtin_nontemporal_store(pk.ll, (unsigned long long*)(hout + (size_t)node * F + lane * 4));
    } else {
        float o0 = acc[0] + sw * b2f(*ps) + bias[lane];
        if (RELU) o0 = fmaxf(o0, 0.f);
        __builtin_nontemporal_store((unsigned short)f2b(o0), hout + (size_t)node * F + lane);
    }
}

// ---------------- edge head: out[e] = sigmoid(relu(u[a]+u[b]+bl1) . Wl2 + bl2) ----------------

__global__ __launch_bounds__(256) void edge_head_kernel(
    const int* __restrict__ pos, const int* __restrict__ neg,
    const unsigned short* __restrict__ u,
    const float* __restrict__ bl1, const float* __restrict__ Wl2,
    const float* __restrict__ bl2, float* __restrict__ out)
{
    int tid = threadIdx.x;
    int wv = tid >> 6, lane = tid & 63;
    int sub = lane >> 4, fl = lane & 15;
    int e = blockIdx.x * 16 + wv * 4 + sub;
    if (e >= ETEST) return;
    int a, b;
    if (e < EPOS) { a = pos[e]; b = pos[EPOS + e]; }
    else { int i = e - EPOS; a = neg[i]; b = neg[EPOS + i]; }
    uint2 qa = *(const uint2*)&u[(size_t)a * 64 + fl * 4];
    uint2 qb = *(const uint2*)&u[(size_t)b * 64 + fl * 4];
    float4 b1 = *(const float4*)&bl1[fl * 4];
    float4 w2 = *(const float4*)&Wl2[fl * 4];
    float s = fmaxf(blo(qa.x) + blo(qb.x) + b1.x, 0.f) * w2.x
            + fmaxf(bhi(qa.x) + bhi(qb.x) + b1.y, 0.f) * w2.y
            + fmaxf(blo(qa.y) + blo(qb.y) + b1.z, 0.f) * w2.z
            + fmaxf(bhi(qa.y) + bhi(qb.y) + b1.w, 0.f) * w2.w;
    #pragma unroll
    for (int off = 8; off > 0; off >>= 1)
        s += __shfl_xor(s, off);     // stays within the 16-lane group
    if (fl == 0)
        out[e] = 1.0f / (1.0f + expf(-(s + bl2[0])));
}

// ---------------- launch ----------------

extern "C" void kernel_launch(void* const* d_in, const int* in_sizes, int n_in,
                              void* d_out, int out_size, void* d_ws, size_t ws_size,
                              hipStream_t stream) {
    const float* x   = (const float*)d_in[0];
    const int*   tei = (const int*)d_in[1];
    const int*   pos = (const int*)d_in[2];
    const int*   neg = (const int*)d_in[3];
    const float* W1  = (const float*)d_in[4];
    const float* b1  = (const float*)d_in[5];
    const float* W2  = (const float*)d_in[6];
    const float* b2  = (const float*)d_in[7];
    const float* Wl1 = (const float*)d_in[8];
    const float* bl1 = (const float*)d_in[9];
    const float* Wl2 = (const float*)d_in[10];
    const float* bl2 = (const float*)d_in[11];
    float* out = (float*)d_out;

    // workspace (4B-word offsets, ~71.4MB)
    float* fws = (float*)d_ws;
    int*   iws = (int*)d_ws;
    unsigned short* usws = (unsigned short*)d_ws;
    float* dinv     = fws;                         // [50000]
    int*   deg      = iws + 50000;                 // [50000]
    int*   ptr      = iws + 100000;                // [50001]
    int*   cursor   = iws + 150002;                // [50000]
    int2*  edat     = (int2*)(iws + 200064);       // [800000] int2 -> ends 1800064
    unsigned short* w1t  = usws + 2ull * 1800192;  // [65536]  -> w 1832960
    unsigned short* wct  = usws + 2ull * 1832960;  // [128*256] -> w 1849344
    float* c2f      = fws + 1849344;               // [64]
    unsigned short* bufL16 = usws + 2ull * 1853504;  // h1lin [12.8M us] -> w 8253504
    unsigned short* bufH   = usws + 2ull * 8253504;  // h1 [12.8M us] -> w 14653504
    unsigned short* vbuf   = usws + 2ull * 14653504; // v [3.2M us] -> w 16253504
    unsigned short* ubuf   = usws + 2ull * 16253504; // u [3.2M us] -> w 17853504

    hipMemsetAsync(deg, 0, NV * sizeof(int), stream);

    // fat0: deg histogram + cvt(W1) + Wc/c2
    fat0_kernel<<<3510, 256, 0, stream>>>(tei, deg, W1, w1t, W2, Wl1, b2, wct, c2f);

    // self-sufficient CSR scan (ptr, cursor, dinv)
    ptr2_kernel<<<49, 1024, 0, stream>>>(deg, ptr, cursor, dinv);

    // fat1: gemm1 (h1lin = bf16(x) @ w1t) + fill(edat)
    fat1_kernel<<<3907, 256, 0, stream>>>(x, w1t, bufL16, tei, dinv, cursor, edat);

    // layer 1 gather: h1 = relu(gather(h1lin) + b1)
    gather_kernel<256, true><<<(NV * 64) / 256, 256, 0, stream>>>(ptr, edat, dinv, bufL16, b1, bufH);

    // v = h1 @ (W2@Wl1); u = gather(v) + c2  (layer-2 agg and Wl1 fused algebraically)
    gemm_v_kernel<<<391, 256, 0, stream>>>(bufH, wct, vbuf);
    gather_kernel<64, false><<<(NV * 64) / 256, 256, 0, stream>>>(ptr, edat, dinv, vbuf, c2f, ubuf);

    // edge head on u
    edge_head_kernel<<<ETEST / 16, 256, 0, stream>>>(pos, neg, ubuf, bl1, Wl2, bl2, out);
}